// Round 6
// baseline (1004.477 us; speedup 1.0000x reference)
//
#include <hip/hip_runtime.h>
#include <cmath>

constexpr int BB = 8, TT = 96, EE = 96, CC = 256, HHD = 8, DDm = 32;
constexpr int NTOK = BB * TT * EE;   // 73728
constexpr int TOUT = TT / 2;         // 48

typedef unsigned short u16;
typedef short bf16x8 __attribute__((ext_vector_type(8)));
typedef float f32x4 __attribute__((ext_vector_type(4)));

__device__ __forceinline__ float bf2f(u16 u) {
  union { unsigned int i; float f; } v; v.i = ((unsigned int)u) << 16; return v.f;
}
__device__ __forceinline__ u16 f2bf(float f) {
  union { unsigned int i; float f; } v; v.f = f;
  return (u16)((v.i + 0x7FFFu + ((v.i >> 16) & 1u)) >> 16);  // RNE
}
__device__ __forceinline__ float wsum(float v) {
#pragma unroll
  for (int off = 32; off; off >>= 1) v += __shfl_xor(v, off);
  return v;
}
__device__ __forceinline__ float gelu_f(float x) {
  return 0.5f * x * (1.0f + erff(x * 0.70710678118654752f));
}

// -------- weight transpose+convert: W fp32 [K][Nc] -> Wt bf16 [Nc][K] --------
__global__ void k_transpose(const float* __restrict__ in, u16* __restrict__ out, int K, int Nc, int n) {
  int idx = blockIdx.x * 256 + threadIdx.x;
  if (idx < n) {
    int k = idx / Nc, c = idx - k * Nc;
    out[c * K + k] = f2bf(in[idx]);
  }
}

// -------- fp32 -> bf16 convert (adj) --------
__global__ void k_cvt(const float* __restrict__ in, u16* __restrict__ out, int n) {
  int idx = blockIdx.x * 256 + threadIdx.x;
  if (idx < n) out[idx] = f2bf(in[idx]);
}

// ------- LN of fp32 input x -> X fp32 copy + A = LN(x)*g+b (bf16) -------
__global__ __launch_bounds__(256) void k_ln_in(const float* __restrict__ x, float* __restrict__ X,
                                               u16* __restrict__ A, const float* __restrict__ g,
                                               const float* __restrict__ b) {
  int wv = threadIdx.x >> 6, lane = threadIdx.x & 63;
  long tok = (long)blockIdx.x * 4 + wv;
  int c = lane * 4;
  long off = tok * CC + c;
  float4 v = *(const float4*)(x + off);
  float s = v.x + v.y + v.z + v.w;
  float sq = v.x * v.x + v.y * v.y + v.z * v.z + v.w * v.w;
  s = wsum(s); sq = wsum(sq);
  float m = s * (1.0f / CC);
  float rs = rsqrtf(sq * (1.0f / CC) - m * m + 1e-5f);
  *(float4*)(X + off) = v;
  float4 gv = *(const float4*)(g + c);
  float4 bv = *(const float4*)(b + c);
  ushort4 o;
  o.x = f2bf((v.x - m) * rs * gv.x + bv.x);
  o.y = f2bf((v.y - m) * rs * gv.y + bv.y);
  o.z = f2bf((v.z - m) * rs * gv.z + bv.z);
  o.w = f2bf((v.w - m) * rs * gv.w + bv.w);
  *(ushort4*)(A + off) = o;
}

// ---------------- A = LN(X fp32)*g+b ----------------
__global__ __launch_bounds__(256) void k_ln_f32(const float* __restrict__ X, u16* __restrict__ A,
                                                const float* __restrict__ g, const float* __restrict__ b) {
  int wv = threadIdx.x >> 6, lane = threadIdx.x & 63;
  long tok = (long)blockIdx.x * 4 + wv;
  int c = lane * 4;
  long off = tok * CC + c;
  float4 v = *(const float4*)(X + off);
  float s = v.x + v.y + v.z + v.w;
  float sq = v.x * v.x + v.y * v.y + v.z * v.z + v.w * v.w;
  s = wsum(s); sq = wsum(sq);
  float m = s * (1.0f / CC);
  float rs = rsqrtf(sq * (1.0f / CC) - m * m + 1e-5f);
  float4 gv = *(const float4*)(g + c);
  float4 bv = *(const float4*)(b + c);
  ushort4 o;
  o.x = f2bf((v.x - m) * rs * gv.x + bv.x);
  o.y = f2bf((v.y - m) * rs * gv.y + bv.y);
  o.z = f2bf((v.z - m) * rs * gv.z + bv.z);
  o.w = f2bf((v.w - m) * rs * gv.w + bv.w);
  *(ushort4*)(A + off) = o;
}

// ------- spatial combine: xs = LN1(X); o = LN(P)*s_ng+s_nb; X += xs + s_gamma*o; A = LN2(X) -------
__global__ __launch_bounds__(256) void k_sp_combine(float* __restrict__ X, u16* __restrict__ A,
                                                    const u16* __restrict__ P,
                                                    const float* __restrict__ n1g, const float* __restrict__ n1b,
                                                    const float* __restrict__ sg,
                                                    const float* __restrict__ s_ng, const float* __restrict__ s_nb,
                                                    const float* __restrict__ n2g, const float* __restrict__ n2b) {
  int wv = threadIdx.x >> 6, lane = threadIdx.x & 63;
  long tok = (long)blockIdx.x * 4 + wv;
  int c = lane * 4;
  long off = tok * CC + c;
  float4 xv = *(const float4*)(X + off);
  // recompute xs = LN1(x) in fp32
  float s1 = xv.x + xv.y + xv.z + xv.w;
  float q1 = xv.x * xv.x + xv.y * xv.y + xv.z * xv.z + xv.w * xv.w;
  s1 = wsum(s1); q1 = wsum(q1);
  float m1 = s1 * (1.0f / CC);
  float r1 = rsqrtf(q1 * (1.0f / CC) - m1 * m1 + 1e-5f);
  float4 g1 = *(const float4*)(n1g + c);
  float4 b1 = *(const float4*)(n1b + c);
  float xs0 = (xv.x - m1) * r1 * g1.x + b1.x;
  float xs1 = (xv.y - m1) * r1 * g1.y + b1.y;
  float xs2 = (xv.z - m1) * r1 * g1.z + b1.z;
  float xs3 = (xv.w - m1) * r1 * g1.w + b1.w;
  // LN(P)
  ushort4 up = *(const ushort4*)(P + off);
  float4 p = make_float4(bf2f(up.x), bf2f(up.y), bf2f(up.z), bf2f(up.w));
  float s = p.x + p.y + p.z + p.w;
  float sq = p.x * p.x + p.y * p.y + p.z * p.z + p.w * p.w;
  s = wsum(s); sq = wsum(sq);
  float m = s * (1.0f / CC);
  float rs = rsqrtf(sq * (1.0f / CC) - m * m + 1e-5f);
  float4 ug = *(const float4*)(s_ng + c);
  float4 ub = *(const float4*)(s_nb + c);
  float o0 = (p.x - m) * rs * ug.x + ub.x;
  float o1 = (p.y - m) * rs * ug.y + ub.y;
  float o2 = (p.z - m) * rs * ug.z + ub.z;
  float o3 = (p.w - m) * rs * ug.w + ub.w;
  float gsg = sg[0];
  float x0 = xv.x + xs0 + gsg * o0;
  float x1 = xv.y + xs1 + gsg * o1;
  float x2 = xv.z + xs2 + gsg * o2;
  float x3 = xv.w + xs3 + gsg * o3;
  *(float4*)(X + off) = make_float4(x0, x1, x2, x3);
  // LN2 over updated x
  float s2 = x0 + x1 + x2 + x3;
  float sq2 = x0 * x0 + x1 * x1 + x2 * x2 + x3 * x3;
  s2 = wsum(s2); sq2 = wsum(sq2);
  float m2 = s2 * (1.0f / CC);
  float rs2 = rsqrtf(sq2 * (1.0f / CC) - m2 * m2 + 1e-5f);
  float4 g2 = *(const float4*)(n2g + c);
  float4 b2 = *(const float4*)(n2b + c);
  ushort4 o;
  o.x = f2bf((x0 - m2) * rs2 * g2.x + b2.x);
  o.y = f2bf((x1 - m2) * rs2 * g2.y + b2.y);
  o.z = f2bf((x2 - m2) * rs2 * g2.z + b2.z);
  o.w = f2bf((x3 - m2) * rs2 * g2.w + b2.w);
  *(ushort4*)(A + off) = o;
}

// ---------------- GEMM: out[M,Nc] = act[M,Kd](lda) @ Wt[Nc,Kd](ldb)^T ----------------
// epi: 0 = write bf16; 1 = +bias, write bf16; 2 = +bias, gelu, write bf16;
//      3 = (+bias if non-null), X += gamma*val (gamma from gptr, or 1.0 if null)
__global__ __launch_bounds__(256) void k_gemm(const u16* __restrict__ act, const u16* __restrict__ Wt,
                                              const float* __restrict__ bias, const float* __restrict__ gptr,
                                              u16* __restrict__ outB, float* __restrict__ Xacc,
                                              int Kd, int Nc, int lda, int ldb, int epi) {
  __shared__ __align__(16) u16 As[64 * 32];
  __shared__ __align__(16) u16 Bs[64 * 32];
  int m0 = blockIdx.x * 64;
  int n0 = blockIdx.y * 64;
  int tid = threadIdx.x;
  int wv = tid >> 6, lane = tid & 63, lm = lane & 15, quad = lane >> 4;
  int srow = tid >> 2, sseg = tid & 3;
  const u16* ap = act + (long)(m0 + srow) * lda + sseg * 8;
  const u16* bp = Wt + (long)(n0 + srow) * ldb + sseg * 8;
  f32x4 acc[4];
#pragma unroll
  for (int j = 0; j < 4; j++) acc[j] = (f32x4){0.f, 0.f, 0.f, 0.f};
  for (int kk = 0; kk < Kd; kk += 32) {
    *(uint4*)&As[srow * 32 + sseg * 8] = *(const uint4*)(ap + kk);
    *(uint4*)&Bs[srow * 32 + sseg * 8] = *(const uint4*)(bp + kk);
    __syncthreads();
    bf16x8 af = *(const bf16x8*)&As[(wv * 16 + lm) * 32 + quad * 8];
#pragma unroll
    for (int j = 0; j < 4; j++) {
      bf16x8 bfv = *(const bf16x8*)&Bs[(j * 16 + lm) * 32 + quad * 8];
      acc[j] = __builtin_amdgcn_mfma_f32_16x16x32_bf16(af, bfv, acc[j], 0, 0, 0);
    }
    __syncthreads();
  }
  float gm = 1.0f;
  if (epi == 3 && gptr) gm = gptr[0];
#pragma unroll
  for (int j = 0; j < 4; j++) {
    int col = n0 + j * 16 + lm;
    float bv = (epi >= 1 && bias) ? bias[col] : 0.0f;
#pragma unroll
    for (int r = 0; r < 4; r++) {
      int row = m0 + wv * 16 + quad * 4 + r;
      float vv = acc[j][r] + bv;
      if (epi == 2) vv = gelu_f(vv);
      if (epi == 3) Xacc[(long)row * Nc + col] += gm * vv;
      else outB[(long)row * Nc + col] = f2bf(vv);
    }
  }
}

// ---------------- spatial attention: per (b,t,h); S=(QK^T*adj+1)/2 (no softmax); O=S@V ---------
__global__ __launch_bounds__(384) void k_sp_attn(const u16* __restrict__ Q, const u16* __restrict__ K,
                                                 const u16* __restrict__ V, const u16* __restrict__ adj,
                                                 u16* __restrict__ O) {
  __shared__ __align__(16) u16 Qs[96 * 32];
  __shared__ __align__(16) u16 Ks[96 * 32];
  __shared__ __align__(16) u16 Vs[96 * 32];
  __shared__ __align__(16) u16 Ss[96 * 96];  // holds adj first, then S (bf16)
  int blk = blockIdx.x;
  int h = blk & 7, t = (blk >> 3) % TT, b = blk / (8 * TT);
  long base = ((long)(b * TT + t) * EE) * CC + h * DDm;
  int tid = threadIdx.x;
  {
    int row = tid >> 2, seg = tid & 3;
    long goff = base + (long)row * CC + seg * 8;
    *(uint4*)&Qs[row * 32 + seg * 8] = *(const uint4*)(Q + goff);
    *(uint4*)&Ks[row * 32 + seg * 8] = *(const uint4*)(K + goff);
    *(uint4*)&Vs[row * 32 + seg * 8] = *(const uint4*)(V + goff);
#pragma unroll
    for (int i = 0; i < 3; i++) {
      int off = tid * 24 + i * 8;
      *(uint4*)&Ss[off] = *(const uint4*)(adj + off);
    }
  }
  __syncthreads();
  int wv = tid >> 6, lane = tid & 63, lm = lane & 15, quad = lane >> 4;
  bf16x8 aq = *(const bf16x8*)&Qs[(wv * 16 + lm) * 32 + quad * 8];
  f32x4 sc[6];
#pragma unroll
  for (int j = 0; j < 6; j++) {
    bf16x8 bk = *(const bf16x8*)&Ks[(j * 16 + lm) * 32 + quad * 8];
    f32x4 z = (f32x4){0.f, 0.f, 0.f, 0.f};
    sc[j] = __builtin_amdgcn_mfma_f32_16x16x32_bf16(aq, bk, z, 0, 0, 0);
  }
  u16 sv[6][4];
#pragma unroll
  for (int j = 0; j < 6; j++) {
    int col = j * 16 + lm;
#pragma unroll
    for (int r = 0; r < 4; r++) {
      int row = wv * 16 + quad * 4 + r;
      float a = bf2f(Ss[row * 96 + col]);
      sv[j][r] = f2bf((sc[j][r] * a + 1.0f) * 0.5f);
    }
  }
  __syncthreads();  // all adj reads done before overwrite
#pragma unroll
  for (int j = 0; j < 6; j++) {
    int col = j * 16 + lm;
#pragma unroll
    for (int r = 0; r < 4; r++) Ss[(wv * 16 + quad * 4 + r) * 96 + col] = sv[j][r];
  }
  __syncthreads();
  f32x4 oc[2];
  oc[0] = (f32x4){0.f, 0.f, 0.f, 0.f};
  oc[1] = (f32x4){0.f, 0.f, 0.f, 0.f};
#pragma unroll
  for (int ks = 0; ks < 3; ks++) {
    bf16x8 as = *(const bf16x8*)&Ss[(wv * 16 + lm) * 96 + ks * 32 + quad * 8];
#pragma unroll
    for (int n = 0; n < 2; n++) {
      bf16x8 bv;
#pragma unroll
      for (int jj = 0; jj < 8; jj++)
        bv[jj] = (short)Vs[(ks * 32 + quad * 8 + jj) * 32 + n * 16 + lm];
      oc[n] = __builtin_amdgcn_mfma_f32_16x16x32_bf16(as, bv, oc[n], 0, 0, 0);
    }
  }
#pragma unroll
  for (int n = 0; n < 2; n++)
#pragma unroll
    for (int r = 0; r < 4; r++) {
      int row = wv * 16 + quad * 4 + r;
      int dv = n * 16 + lm;
      O[base + (long)row * CC + dv] = f2bf(oc[n][r]);
    }
}

// ---------------- temporal attention: per (b,e,h); softmax(QK^T/sqrt(D)) @ V ----------------
__global__ __launch_bounds__(384) void k_tp_attn(const u16* __restrict__ Q, const u16* __restrict__ K,
                                                 const u16* __restrict__ V, u16* __restrict__ O) {
  __shared__ __align__(16) u16 Qs[96 * 32];
  __shared__ __align__(16) u16 Ks[96 * 32];
  __shared__ __align__(16) u16 Vs[96 * 32];
  __shared__ float Sf[96 * 97];  // fp32, +1 pad kills stride-96 bank conflicts
  int blk = blockIdx.x;
  int h = blk & 7, e = (blk >> 3) % EE, b = blk / (8 * EE);
  long base = ((long)b * TT * EE + e) * CC + h * DDm;
  const long rstride = (long)EE * CC;
  int tid = threadIdx.x;
  {
    int row = tid >> 2, seg = tid & 3;
    long goff = base + row * rstride + seg * 8;
    *(uint4*)&Qs[row * 32 + seg * 8] = *(const uint4*)(Q + goff);
    *(uint4*)&Ks[row * 32 + seg * 8] = *(const uint4*)(K + goff);
    *(uint4*)&Vs[row * 32 + seg * 8] = *(const uint4*)(V + goff);
  }
  __syncthreads();
  int wv = tid >> 6, lane = tid & 63, lm = lane & 15, quad = lane >> 4;
  bf16x8 aq = *(const bf16x8*)&Qs[(wv * 16 + lm) * 32 + quad * 8];
  f32x4 sc[6];
#pragma unroll
  for (int j = 0; j < 6; j++) {
    bf16x8 bk = *(const bf16x8*)&Ks[(j * 16 + lm) * 32 + quad * 8];
    f32x4 z = (f32x4){0.f, 0.f, 0.f, 0.f};
    sc[j] = __builtin_amdgcn_mfma_f32_16x16x32_bf16(aq, bk, z, 0, 0, 0);
  }
  const float scale = 0.17677669529663687f;  // 1/sqrt(32)
#pragma unroll
  for (int j = 0; j < 6; j++) {
    int col = j * 16 + lm;
#pragma unroll
    for (int r = 0; r < 4; r++) Sf[(wv * 16 + quad * 4 + r) * 97 + col] = sc[j][r] * scale;
  }
  __syncthreads();
  if (tid < 96) {
    float mx = -1e30f;
    for (int k2 = 0; k2 < 96; k2++) mx = fmaxf(mx, Sf[tid * 97 + k2]);
    float sum = 0.f;
    for (int k2 = 0; k2 < 96; k2++) {
      float ev = __expf(Sf[tid * 97 + k2] - mx);
      Sf[tid * 97 + k2] = ev;
      sum += ev;
    }
    float inv = 1.0f / sum;
    for (int k2 = 0; k2 < 96; k2++) Sf[tid * 97 + k2] *= inv;
  }
  __syncthreads();
  f32x4 oc[2];
  oc[0] = (f32x4){0.f, 0.f, 0.f, 0.f};
  oc[1] = (f32x4){0.f, 0.f, 0.f, 0.f};
#pragma unroll
  for (int ks = 0; ks < 3; ks++) {
    bf16x8 as;
#pragma unroll
    for (int jj = 0; jj < 8; jj++)
      as[jj] = (short)f2bf(Sf[(wv * 16 + lm) * 97 + ks * 32 + quad * 8 + jj]);
#pragma unroll
    for (int n = 0; n < 2; n++) {
      bf16x8 bv;
#pragma unroll
      for (int jj = 0; jj < 8; jj++)
        bv[jj] = (short)Vs[(ks * 32 + quad * 8 + jj) * 32 + n * 16 + lm];
      oc[n] = __builtin_amdgcn_mfma_f32_16x16x32_bf16(as, bv, oc[n], 0, 0, 0);
    }
  }
#pragma unroll
  for (int n = 0; n < 2; n++)
#pragma unroll
    for (int r = 0; r < 4; r++) {
      int row = wv * 16 + quad * 4 + r;  // t index
      int dv = n * 16 + lm;
      O[((long)(b * TT + row) * EE + e) * CC + h * DDm + dv] = f2bf(oc[n][r]);
    }
}

// ------- downsample: out[b,i,e,c] = 0.5*(X[b,2i,e,c] + X[b,2i+1,e,c])  (fp32 OUT!) -------
__global__ __launch_bounds__(256) void k_down(const float* __restrict__ X, float* __restrict__ out) {
  long i4 = ((long)blockIdx.x * 256 + threadIdx.x) * 4;
  long tmp = i4;
  int c = (int)(tmp & 255); tmp >>= 8;
  int e = (int)(tmp % EE); tmp /= EE;
  int i = (int)(tmp % TOUT);
  int b = (int)(tmp / TOUT);
  long src0 = (((long)b * TT + 2 * i) * EE + e) * CC + c;
  float4 a = *(const float4*)(X + src0);
  float4 bb = *(const float4*)(X + src0 + (long)EE * CC);
  float4 o = make_float4(0.5f * (a.x + bb.x), 0.5f * (a.y + bb.y),
                         0.5f * (a.z + bb.z), 0.5f * (a.w + bb.w));
  *(float4*)(out + i4) = o;
}

extern "C" void kernel_launch(void* const* d_in, const int* in_sizes, int n_in,
                              void* d_out, int out_size, void* d_ws, size_t ws_size,
                              hipStream_t stream) {
  (void)in_sizes; (void)n_in; (void)out_size; (void)ws_size;
  const float* x   = (const float*)d_in[0];
  const float* adj = (const float*)d_in[1];
  const float* n1g = (const float*)d_in[2];
  const float* n1b = (const float*)d_in[3];
  const float* swq = (const float*)d_in[4];
  const float* swk = (const float*)d_in[5];
  const float* swv = (const float*)d_in[6];
  const float* swp = (const float*)d_in[7];
  const float* sbp = (const float*)d_in[8];
  const float* sng = (const float*)d_in[9];
  const float* snb = (const float*)d_in[10];
  const float* sg  = (const float*)d_in[11];
  const float* n2g = (const float*)d_in[12];
  const float* n2b = (const float*)d_in[13];
  const float* twq = (const float*)d_in[14];
  const float* twk = (const float*)d_in[15];
  const float* twv = (const float*)d_in[16];
  const float* twp = (const float*)d_in[17];
  const float* tbp = (const float*)d_in[18];
  const float* tg  = (const float*)d_in[19];
  const float* n3g = (const float*)d_in[20];
  const float* n3b = (const float*)d_in[21];
  const float* mw1 = (const float*)d_in[22];
  const float* mb1 = (const float*)d_in[23];
  const float* mw2 = (const float*)d_in[24];
  const float* mb2 = (const float*)d_in[25];
  float* out = (float*)d_out;   // reference output dtype is float32

  // ---- workspace layout (aliased; peak ~227 MB) ----
  size_t nc = (size_t)NTOK * CC;          // 18,874,368
  float* X  = (float*)d_ws;               // fp32 residual: 75.5 MB
  u16* A    = (u16*)(X + nc);             // 37.7 MB (xs / spO / LN2 / tpO / xm)
  u16* Qb   = A + nc;                     // 37.7 MB
  u16* Kb   = Qb + nc;                    // 37.7 MB
  u16* Vb   = Kb + nc;                    // 37.7 MB
  u16* Hh   = Qb;                         // MLP half-hidden [N,512] spans Qb+Kb
  u16* wts  = Vb + nc;                    // bf16 weights: ~1.2 MB
  u16* swq_t = wts;            u16* swk_t = swq_t + 65536;
  u16* swv_t = swk_t + 65536;  u16* swp_t = swv_t + 65536;
  u16* twq_t = swp_t + 65536;  u16* twk_t = twq_t + 65536;
  u16* twv_t = twk_t + 65536;  u16* twp_t = twv_t + 65536;
  u16* w1_t  = twp_t + 65536;  // [1024,256]
  u16* w2_t  = w1_t + 262144;  // [256,1024]
  u16* adj_b = w2_t + 262144;  // [96,96] bf16

  auto tr = [&](const float* w, u16* dst, int K, int Nc) {
    int n = K * Nc;
    k_transpose<<<(n + 255) / 256, 256, 0, stream>>>(w, dst, K, Nc, n);
  };
  tr(swq, swq_t, 256, 256); tr(swk, swk_t, 256, 256);
  tr(swv, swv_t, 256, 256); tr(swp, swp_t, 256, 256);
  tr(twq, twq_t, 256, 256); tr(twk, twk_t, 256, 256);
  tr(twv, twv_t, 256, 256); tr(twp, twp_t, 256, 256);
  tr(mw1, w1_t, 256, 1024); tr(mw2, w2_t, 1024, 256);
  k_cvt<<<(EE * EE + 255) / 256, 256, 0, stream>>>(adj, adj_b, EE * EE);

  auto gemm = [&](const u16* act, const u16* Wt, const float* bias, const float* gamma,
                  u16* outB, float* Xacc, int Kd, int Nc, int lda, int ldb, int epi) {
    dim3 g(NTOK / 64, Nc / 64);
    k_gemm<<<g, 256, 0, stream>>>(act, Wt, bias, gamma, outB, Xacc, Kd, Nc, lda, ldb, epi);
  };

  int lnBlocks = NTOK / 4;

  // ---- spatial block ----
  k_ln_in<<<lnBlocks, 256, 0, stream>>>(x, X, A, n1g, n1b);               // X=x fp32, A=xs
  gemm(A, swq_t, nullptr, nullptr, Qb, nullptr, 256, 256, 256, 256, 0);
  gemm(A, swk_t, nullptr, nullptr, Kb, nullptr, 256, 256, 256, 256, 0);
  gemm(A, swv_t, nullptr, nullptr, Vb, nullptr, 256, 256, 256, 256, 0);
  k_sp_attn<<<BB * TT * HHD, 384, 0, stream>>>(Qb, Kb, Vb, adj_b, A);     // O -> A
  gemm(A, swp_t, sbp, nullptr, Qb, nullptr, 256, 256, 256, 256, 1);       // P -> Qb
  k_sp_combine<<<lnBlocks, 256, 0, stream>>>(X, A, Qb, n1g, n1b, sg, sng, snb, n2g, n2b);

  // ---- temporal block ----
  gemm(A, twq_t, nullptr, nullptr, Qb, nullptr, 256, 256, 256, 256, 0);
  gemm(A, twk_t, nullptr, nullptr, Kb, nullptr, 256, 256, 256, 256, 0);
  gemm(A, twv_t, nullptr, nullptr, Vb, nullptr, 256, 256, 256, 256, 0);
  k_tp_attn<<<BB * EE * HHD, 384, 0, stream>>>(Qb, Kb, Vb, A);            // O -> A
  gemm(A, twp_t, tbp, tg, nullptr, X, 256, 256, 256, 256, 3);             // X += t_gamma*(o@t_wp+t_bp)

  // ---- MLP (hidden split into two 512-halves through Hh = Qb..Kb) ----
  k_ln_f32<<<lnBlocks, 256, 0, stream>>>(X, A, n3g, n3b);                 // A = xm
  gemm(A, w1_t,             mb1,       nullptr, Hh, nullptr, 256, 512, 256, 256, 2);
  gemm(Hh, w2_t,            mb2,       nullptr, nullptr, X, 512, 256, 512, 1024, 3);
  gemm(A, w1_t + 512 * 256, mb1 + 512, nullptr, Hh, nullptr, 256, 512, 256, 256, 2);
  gemm(Hh, w2_t + 512,      nullptr,   nullptr, nullptr, X, 512, 256, 512, 1024, 3);

  // ---- downsample (fp32 output) ----
  long outElems = (long)BB * TOUT * EE * CC;                              // 9,437,184
  k_down<<<(int)(outElems / 4 / 256), 256, 0, stream>>>(X, out);
}

// Round 7
// 996.802 us; speedup vs baseline: 1.0077x; 1.0077x over previous
//
#include <hip/hip_runtime.h>
#include <cmath>

constexpr int BB = 8, TT = 96, EE = 96, CC = 256, HHD = 8, DDm = 32;
constexpr int NTOK = BB * TT * EE;   // 73728
constexpr int TOUT = TT / 2;         // 48

typedef unsigned short u16;
typedef short bf16x8 __attribute__((ext_vector_type(8)));
typedef float f32x4 __attribute__((ext_vector_type(4)));

__device__ __forceinline__ float bf2f(u16 u) {
  union { unsigned int i; float f; } v; v.i = ((unsigned int)u) << 16; return v.f;
}
__device__ __forceinline__ u16 f2bf(float f) {
  union { unsigned int i; float f; } v; v.f = f;
  return (u16)((v.i + 0x7FFFu + ((v.i >> 16) & 1u)) >> 16);  // RNE
}
__device__ __forceinline__ float wsum(float v) {
#pragma unroll
  for (int off = 32; off; off >>= 1) v += __shfl_xor(v, off);
  return v;
}
__device__ __forceinline__ float gelu_f(float x) {
  return 0.5f * x * (1.0f + erff(x * 0.70710678118654752f));
}
// token-order permutations: 0=id, 1=[b,t,e]->[b,e,t] position, 2=[b,e,t]->[b,t,e]
__device__ __forceinline__ int remap_row(int row, int mode) {
  if (mode == 0) return row;
  int b = row / (TT * EE);
  int rem = row - b * (TT * EE);
  if (mode == 1) { int t = rem / EE, e = rem - t * EE; return (b * EE + e) * TT + t; }
  int e = rem / TT, t = rem - e * TT;
  return (b * TT + t) * EE + e;
}

// -------- weight transpose+convert: W fp32 [K][Nc] -> Wt bf16 [Nc][K] --------
__global__ void k_transpose(const float* __restrict__ in, u16* __restrict__ out, int K, int Nc, int n) {
  int idx = blockIdx.x * 256 + threadIdx.x;
  if (idx < n) {
    int k = idx / Nc, c = idx - k * Nc;
    out[c * K + k] = f2bf(in[idx]);
  }
}

// -------- fp32 -> bf16 convert (adj) --------
__global__ void k_cvt(const float* __restrict__ in, u16* __restrict__ out, int n) {
  int idx = blockIdx.x * 256 + threadIdx.x;
  if (idx < n) out[idx] = f2bf(in[idx]);
}

// ------- LN of fp32 input x -> X fp32 copy + A = LN(x)*g+b (bf16) -------
__global__ __launch_bounds__(256) void k_ln_in(const float* __restrict__ x, float* __restrict__ X,
                                               u16* __restrict__ A, const float* __restrict__ g,
                                               const float* __restrict__ b) {
  int wv = threadIdx.x >> 6, lane = threadIdx.x & 63;
  long tok = (long)blockIdx.x * 4 + wv;
  int c = lane * 4;
  long off = tok * CC + c;
  float4 v = *(const float4*)(x + off);
  float s = v.x + v.y + v.z + v.w;
  float sq = v.x * v.x + v.y * v.y + v.z * v.z + v.w * v.w;
  s = wsum(s); sq = wsum(sq);
  float m = s * (1.0f / CC);
  float rs = rsqrtf(sq * (1.0f / CC) - m * m + 1e-5f);
  *(float4*)(X + off) = v;
  float4 gv = *(const float4*)(g + c);
  float4 bv = *(const float4*)(b + c);
  ushort4 o;
  o.x = f2bf((v.x - m) * rs * gv.x + bv.x);
  o.y = f2bf((v.y - m) * rs * gv.y + bv.y);
  o.z = f2bf((v.z - m) * rs * gv.z + bv.z);
  o.w = f2bf((v.w - m) * rs * gv.w + bv.w);
  *(ushort4*)(A + off) = o;
}

// ---------------- A = LN(X fp32)*g+b ----------------
__global__ __launch_bounds__(256) void k_ln_f32(const float* __restrict__ X, u16* __restrict__ A,
                                                const float* __restrict__ g, const float* __restrict__ b) {
  int wv = threadIdx.x >> 6, lane = threadIdx.x & 63;
  long tok = (long)blockIdx.x * 4 + wv;
  int c = lane * 4;
  long off = tok * CC + c;
  float4 v = *(const float4*)(X + off);
  float s = v.x + v.y + v.z + v.w;
  float sq = v.x * v.x + v.y * v.y + v.z * v.z + v.w * v.w;
  s = wsum(s); sq = wsum(sq);
  float m = s * (1.0f / CC);
  float rs = rsqrtf(sq * (1.0f / CC) - m * m + 1e-5f);
  float4 gv = *(const float4*)(g + c);
  float4 bv = *(const float4*)(b + c);
  ushort4 o;
  o.x = f2bf((v.x - m) * rs * gv.x + bv.x);
  o.y = f2bf((v.y - m) * rs * gv.y + bv.y);
  o.z = f2bf((v.z - m) * rs * gv.z + bv.z);
  o.w = f2bf((v.w - m) * rs * gv.w + bv.w);
  *(ushort4*)(A + off) = o;
}

// ------- spatial combine: xs = LN1(X); o = LN(P)*s_ng+s_nb; X += xs + s_gamma*o; A = LN2(X) -------
__global__ __launch_bounds__(256) void k_sp_combine(float* __restrict__ X, u16* __restrict__ A,
                                                    const u16* __restrict__ P,
                                                    const float* __restrict__ n1g, const float* __restrict__ n1b,
                                                    const float* __restrict__ sg,
                                                    const float* __restrict__ s_ng, const float* __restrict__ s_nb,
                                                    const float* __restrict__ n2g, const float* __restrict__ n2b) {
  int wv = threadIdx.x >> 6, lane = threadIdx.x & 63;
  long tok = (long)blockIdx.x * 4 + wv;
  int c = lane * 4;
  long off = tok * CC + c;
  float4 xv = *(const float4*)(X + off);
  float s1 = xv.x + xv.y + xv.z + xv.w;
  float q1 = xv.x * xv.x + xv.y * xv.y + xv.z * xv.z + xv.w * xv.w;
  s1 = wsum(s1); q1 = wsum(q1);
  float m1 = s1 * (1.0f / CC);
  float r1 = rsqrtf(q1 * (1.0f / CC) - m1 * m1 + 1e-5f);
  float4 g1 = *(const float4*)(n1g + c);
  float4 b1 = *(const float4*)(n1b + c);
  float xs0 = (xv.x - m1) * r1 * g1.x + b1.x;
  float xs1 = (xv.y - m1) * r1 * g1.y + b1.y;
  float xs2 = (xv.z - m1) * r1 * g1.z + b1.z;
  float xs3 = (xv.w - m1) * r1 * g1.w + b1.w;
  ushort4 up = *(const ushort4*)(P + off);
  float4 p = make_float4(bf2f(up.x), bf2f(up.y), bf2f(up.z), bf2f(up.w));
  float s = p.x + p.y + p.z + p.w;
  float sq = p.x * p.x + p.y * p.y + p.z * p.z + p.w * p.w;
  s = wsum(s); sq = wsum(sq);
  float m = s * (1.0f / CC);
  float rs = rsqrtf(sq * (1.0f / CC) - m * m + 1e-5f);
  float4 ug = *(const float4*)(s_ng + c);
  float4 ub = *(const float4*)(s_nb + c);
  float o0 = (p.x - m) * rs * ug.x + ub.x;
  float o1 = (p.y - m) * rs * ug.y + ub.y;
  float o2 = (p.z - m) * rs * ug.z + ub.z;
  float o3 = (p.w - m) * rs * ug.w + ub.w;
  float gsg = sg[0];
  float x0 = xv.x + xs0 + gsg * o0;
  float x1 = xv.y + xs1 + gsg * o1;
  float x2 = xv.z + xs2 + gsg * o2;
  float x3 = xv.w + xs3 + gsg * o3;
  *(float4*)(X + off) = make_float4(x0, x1, x2, x3);
  float s2 = x0 + x1 + x2 + x3;
  float sq2 = x0 * x0 + x1 * x1 + x2 * x2 + x3 * x3;
  s2 = wsum(s2); sq2 = wsum(sq2);
  float m2 = s2 * (1.0f / CC);
  float rs2 = rsqrtf(sq2 * (1.0f / CC) - m2 * m2 + 1e-5f);
  float4 g2 = *(const float4*)(n2g + c);
  float4 b2 = *(const float4*)(n2b + c);
  ushort4 o;
  o.x = f2bf((x0 - m2) * rs2 * g2.x + b2.x);
  o.y = f2bf((x1 - m2) * rs2 * g2.y + b2.y);
  o.z = f2bf((x2 - m2) * rs2 * g2.z + b2.z);
  o.w = f2bf((x3 - m2) * rs2 * g2.w + b2.w);
  *(ushort4*)(A + off) = o;
}

// ---- 128x128-tile MFMA GEMM: out[M,Nc] = act[M,Kd](lda) @ Wt[Nc,Kd](ldb)^T ----
// epi: 0 plain; 1 +bias; 2 +bias,gelu; 3 (+bias), Xacc += gamma*val
// remap permutes the OUTPUT row (token) index.
__global__ __launch_bounds__(256) void k_gemm128(const u16* __restrict__ act, const u16* __restrict__ Wt,
                                                 const float* __restrict__ bias, const float* __restrict__ gptr,
                                                 u16* __restrict__ outB, float* __restrict__ Xacc,
                                                 int Kd, int Nc, int lda, int ldb, int epi, int remap) {
  __shared__ __align__(16) u16 As[128 * 32];   // 8 KB
  __shared__ __align__(16) u16 Bs[128 * 32];   // 8 KB
  int m0 = blockIdx.x * 128, n0 = blockIdx.y * 128;
  int tid = threadIdx.x;
  int wv = tid >> 6, lane = tid & 63, lm = lane & 15, quad = lane >> 4;
  int wr = wv >> 1, wc = wv & 1;               // wave's 64x64 quadrant
  f32x4 acc[4][4];
#pragma unroll
  for (int i = 0; i < 4; i++)
#pragma unroll
    for (int j = 0; j < 4; j++) acc[i][j] = (f32x4){0.f, 0.f, 0.f, 0.f};

  for (int kk = 0; kk < Kd; kk += 32) {
    // stage A and B tiles: 512 16B-chunks each; chunk cid -> row=cid>>2, seg=cid&3
    // LDS layout As[row*32 + seg*8] == As[cid*8]; wave-uniform base + lane*16 matches HW.
#pragma unroll
    for (int j = 0; j < 2; j++) {
      int cid = j * 256 + wv * 64 + lane;
      int row = cid >> 2, seg = cid & 3;
      const u16* ga = act + (long)(m0 + row) * lda + kk + seg * 8;
      const u16* gb = Wt + (long)(n0 + row) * ldb + kk + seg * 8;
      u16* la = &As[(j * 256 + wv * 64) * 8];
      u16* lb = &Bs[(j * 256 + wv * 64) * 8];
      __builtin_amdgcn_global_load_lds(ga, la, 16, 0, 0);
      __builtin_amdgcn_global_load_lds(gb, lb, 16, 0, 0);
    }
    __syncthreads();
    bf16x8 af[4], bfv[4];
#pragma unroll
    for (int t = 0; t < 4; t++) {
      af[t] = *(const bf16x8*)&As[(wr * 64 + t * 16 + lm) * 32 + quad * 8];
      bfv[t] = *(const bf16x8*)&Bs[(wc * 64 + t * 16 + lm) * 32 + quad * 8];
    }
#pragma unroll
    for (int ti = 0; ti < 4; ti++)
#pragma unroll
      for (int tj = 0; tj < 4; tj++)
        acc[ti][tj] = __builtin_amdgcn_mfma_f32_16x16x32_bf16(af[ti], bfv[tj], acc[ti][tj], 0, 0, 0);
    __syncthreads();
  }

  float gm = (epi == 3 && gptr) ? gptr[0] : 1.0f;
  int orows[16];
#pragma unroll
  for (int ti = 0; ti < 4; ti++)
#pragma unroll
    for (int r = 0; r < 4; r++)
      orows[ti * 4 + r] = remap_row(m0 + wr * 64 + ti * 16 + quad * 4 + r, remap);
#pragma unroll
  for (int tj = 0; tj < 4; tj++) {
    int col = n0 + wc * 64 + tj * 16 + lm;
    float bv = (epi >= 1 && bias) ? bias[col] : 0.0f;
#pragma unroll
    for (int ti = 0; ti < 4; ti++)
#pragma unroll
      for (int r = 0; r < 4; r++) {
        float vv = acc[ti][tj][r] + bv;
        if (epi == 2) vv = gelu_f(vv);
        long off = (long)orows[ti * 4 + r] * Nc + col;
        if (epi == 3) Xacc[off] += gm * vv;
        else outB[off] = f2bf(vv);
      }
  }
}

// ---- spatial attention: per (b,t,h); QKV interleaved [N,768]; S=(QK^T*adj+1)/2; O=S@V -> O[N,256] ----
__global__ __launch_bounds__(384) void k_sp_attn(const u16* __restrict__ QKV, const u16* __restrict__ adj,
                                                 u16* __restrict__ O) {
  __shared__ __align__(16) u16 Qs[96 * 32];
  __shared__ __align__(16) u16 Ks[96 * 32];
  __shared__ __align__(16) u16 Vs[96 * 32];
  __shared__ __align__(16) u16 Ss[96 * 96];
  int blk = blockIdx.x;
  int h = blk & 7, t = (blk >> 3) % TT, b = blk / (8 * TT);
  long base = ((long)(b * TT + t) * EE) * 768 + h * DDm;
  int tid = threadIdx.x;
  {
    int row = tid >> 2, seg = tid & 3;
    long goff = base + (long)row * 768 + seg * 8;
    *(uint4*)&Qs[row * 32 + seg * 8] = *(const uint4*)(QKV + goff);
    *(uint4*)&Ks[row * 32 + seg * 8] = *(const uint4*)(QKV + goff + 256);
    *(uint4*)&Vs[row * 32 + seg * 8] = *(const uint4*)(QKV + goff + 512);
#pragma unroll
    for (int i = 0; i < 3; i++) {
      int off = tid * 24 + i * 8;
      *(uint4*)&Ss[off] = *(const uint4*)(adj + off);
    }
  }
  __syncthreads();
  int wv = tid >> 6, lane = tid & 63, lm = lane & 15, quad = lane >> 4;
  bf16x8 aq = *(const bf16x8*)&Qs[(wv * 16 + lm) * 32 + quad * 8];
  f32x4 sc[6];
#pragma unroll
  for (int j = 0; j < 6; j++) {
    bf16x8 bk = *(const bf16x8*)&Ks[(j * 16 + lm) * 32 + quad * 8];
    f32x4 z = (f32x4){0.f, 0.f, 0.f, 0.f};
    sc[j] = __builtin_amdgcn_mfma_f32_16x16x32_bf16(aq, bk, z, 0, 0, 0);
  }
  u16 sv[6][4];
#pragma unroll
  for (int j = 0; j < 6; j++) {
    int col = j * 16 + lm;
#pragma unroll
    for (int r = 0; r < 4; r++) {
      int row = wv * 16 + quad * 4 + r;
      float a = bf2f(Ss[row * 96 + col]);
      sv[j][r] = f2bf((sc[j][r] * a + 1.0f) * 0.5f);
    }
  }
  __syncthreads();
#pragma unroll
  for (int j = 0; j < 6; j++) {
    int col = j * 16 + lm;
#pragma unroll
    for (int r = 0; r < 4; r++) Ss[(wv * 16 + quad * 4 + r) * 96 + col] = sv[j][r];
  }
  __syncthreads();
  f32x4 oc[2];
  oc[0] = (f32x4){0.f, 0.f, 0.f, 0.f};
  oc[1] = (f32x4){0.f, 0.f, 0.f, 0.f};
#pragma unroll
  for (int ks = 0; ks < 3; ks++) {
    bf16x8 as = *(const bf16x8*)&Ss[(wv * 16 + lm) * 96 + ks * 32 + quad * 8];
#pragma unroll
    for (int n = 0; n < 2; n++) {
      bf16x8 bv;
#pragma unroll
      for (int jj = 0; jj < 8; jj++)
        bv[jj] = (short)Vs[(ks * 32 + quad * 8 + jj) * 32 + n * 16 + lm];
      oc[n] = __builtin_amdgcn_mfma_f32_16x16x32_bf16(as, bv, oc[n], 0, 0, 0);
    }
  }
  long obase = ((long)(b * TT + t) * EE) * CC + h * DDm;
#pragma unroll
  for (int n = 0; n < 2; n++)
#pragma unroll
    for (int r = 0; r < 4; r++) {
      int row = wv * 16 + quad * 4 + r;
      O[obase + (long)row * CC + n * 16 + lm] = f2bf(oc[n][r]);
    }
}

// ---- temporal attention: per (b,e,h); QKV in [b,e,t] order [N,768]; softmax; O in [b,e,t] [N,256] ----
__global__ __launch_bounds__(384) void k_tp_attn(const u16* __restrict__ QKV, u16* __restrict__ O) {
  __shared__ __align__(16) u16 Qs[96 * 32];
  __shared__ __align__(16) u16 Ks[96 * 32];
  __shared__ __align__(16) u16 Vs[96 * 32];
  __shared__ float Sf[96 * 97];
  int blk = blockIdx.x;
  int h = blk & 7, e = (blk >> 3) % EE, b = blk / (8 * EE);
  long base = ((long)(b * EE + e) * TT) * 768 + h * DDm;
  int tid = threadIdx.x;
  {
    int row = tid >> 2, seg = tid & 3;
    long goff = base + (long)row * 768 + seg * 8;
    *(uint4*)&Qs[row * 32 + seg * 8] = *(const uint4*)(QKV + goff);
    *(uint4*)&Ks[row * 32 + seg * 8] = *(const uint4*)(QKV + goff + 256);
    *(uint4*)&Vs[row * 32 + seg * 8] = *(const uint4*)(QKV + goff + 512);
  }
  __syncthreads();
  int wv = tid >> 6, lane = tid & 63, lm = lane & 15, quad = lane >> 4;
  bf16x8 aq = *(const bf16x8*)&Qs[(wv * 16 + lm) * 32 + quad * 8];
  f32x4 sc[6];
#pragma unroll
  for (int j = 0; j < 6; j++) {
    bf16x8 bk = *(const bf16x8*)&Ks[(j * 16 + lm) * 32 + quad * 8];
    f32x4 z = (f32x4){0.f, 0.f, 0.f, 0.f};
    sc[j] = __builtin_amdgcn_mfma_f32_16x16x32_bf16(aq, bk, z, 0, 0, 0);
  }
  const float scale = 0.17677669529663687f;  // 1/sqrt(32)
#pragma unroll
  for (int j = 0; j < 6; j++) {
    int col = j * 16 + lm;
#pragma unroll
    for (int r = 0; r < 4; r++) Sf[(wv * 16 + quad * 4 + r) * 97 + col] = sc[j][r] * scale;
  }
  __syncthreads();
  if (tid < 96) {
    float mx = -1e30f;
    for (int k2 = 0; k2 < 96; k2++) mx = fmaxf(mx, Sf[tid * 97 + k2]);
    float sum = 0.f;
    for (int k2 = 0; k2 < 96; k2++) {
      float ev = __expf(Sf[tid * 97 + k2] - mx);
      Sf[tid * 97 + k2] = ev;
      sum += ev;
    }
    float inv = 1.0f / sum;
    for (int k2 = 0; k2 < 96; k2++) Sf[tid * 97 + k2] *= inv;
  }
  __syncthreads();
  f32x4 oc[2];
  oc[0] = (f32x4){0.f, 0.f, 0.f, 0.f};
  oc[1] = (f32x4){0.f, 0.f, 0.f, 0.f};
#pragma unroll
  for (int ks = 0; ks < 3; ks++) {
    bf16x8 as;
#pragma unroll
    for (int jj = 0; jj < 8; jj++)
      as[jj] = (short)f2bf(Sf[(wv * 16 + lm) * 97 + ks * 32 + quad * 8 + jj]);
#pragma unroll
    for (int n = 0; n < 2; n++) {
      bf16x8 bv;
#pragma unroll
      for (int jj = 0; jj < 8; jj++)
        bv[jj] = (short)Vs[(ks * 32 + quad * 8 + jj) * 32 + n * 16 + lm];
      oc[n] = __builtin_amdgcn_mfma_f32_16x16x32_bf16(as, bv, oc[n], 0, 0, 0);
    }
  }
  long obase = ((long)(b * EE + e) * TT) * CC + h * DDm;
#pragma unroll
  for (int n = 0; n < 2; n++)
#pragma unroll
    for (int r = 0; r < 4; r++) {
      int row = wv * 16 + quad * 4 + r;  // t index
      O[obase + (long)row * CC + n * 16 + lm] = f2bf(oc[n][r]);
    }
}

// ------- downsample: out[b,i,e,c] = 0.5*(X[b,2i,e,c] + X[b,2i+1,e,c])  (fp32 out) -------
__global__ __launch_bounds__(256) void k_down(const float* __restrict__ X, float* __restrict__ out) {
  long i4 = ((long)blockIdx.x * 256 + threadIdx.x) * 4;
  long tmp = i4;
  int c = (int)(tmp & 255); tmp >>= 8;
  int e = (int)(tmp % EE); tmp /= EE;
  int i = (int)(tmp % TOUT);
  int b = (int)(tmp / TOUT);
  long src0 = (((long)b * TT + 2 * i) * EE + e) * CC + c;
  float4 a = *(const float4*)(X + src0);
  float4 bb = *(const float4*)(X + src0 + (long)EE * CC);
  float4 o = make_float4(0.5f * (a.x + bb.x), 0.5f * (a.y + bb.y),
                         0.5f * (a.z + bb.z), 0.5f * (a.w + bb.w));
  *(float4*)(out + i4) = o;
}

extern "C" void kernel_launch(void* const* d_in, const int* in_sizes, int n_in,
                              void* d_out, int out_size, void* d_ws, size_t ws_size,
                              hipStream_t stream) {
  (void)in_sizes; (void)n_in; (void)out_size; (void)ws_size;
  const float* x   = (const float*)d_in[0];
  const float* adj = (const float*)d_in[1];
  const float* n1g = (const float*)d_in[2];
  const float* n1b = (const float*)d_in[3];
  const float* swq = (const float*)d_in[4];
  const float* swk = (const float*)d_in[5];
  const float* swv = (const float*)d_in[6];
  const float* swp = (const float*)d_in[7];
  const float* sbp = (const float*)d_in[8];
  const float* sng = (const float*)d_in[9];
  const float* snb = (const float*)d_in[10];
  const float* sg  = (const float*)d_in[11];
  const float* n2g = (const float*)d_in[12];
  const float* n2b = (const float*)d_in[13];
  const float* twq = (const float*)d_in[14];
  const float* twk = (const float*)d_in[15];
  const float* twv = (const float*)d_in[16];
  const float* twp = (const float*)d_in[17];
  const float* tbp = (const float*)d_in[18];
  const float* tg  = (const float*)d_in[19];
  const float* n3g = (const float*)d_in[20];
  const float* n3b = (const float*)d_in[21];
  const float* mw1 = (const float*)d_in[22];
  const float* mb1 = (const float*)d_in[23];
  const float* mw2 = (const float*)d_in[24];
  const float* mb2 = (const float*)d_in[25];
  float* out = (float*)d_out;

  // ---- workspace: X fp32 | A bf16 | QKV bf16 [N,768] | weights  (~228 MB) ----
  size_t nc = (size_t)NTOK * CC;          // 18,874,368
  float* X  = (float*)d_ws;               // 75.5 MB
  u16* A    = (u16*)(X + nc);             // 37.7 MB  (xs / O / LN2 / O_t / xm)
  u16* QKV  = A + nc;                     // 113.2 MB (also P [N,256], Hh [N,512])
  u16* Pb   = QKV;
  u16* Hh   = QKV;
  u16* wts  = QKV + 3 * nc;
  u16* swq_t = wts;            u16* swk_t = swq_t + 65536;
  u16* swv_t = swk_t + 65536;  u16* swp_t = swv_t + 65536;
  u16* twq_t = swp_t + 65536;  u16* twk_t = twq_t + 65536;
  u16* twv_t = twk_t + 65536;  u16* twp_t = twv_t + 65536;
  u16* w1_t  = twp_t + 65536;  // [1024,256]
  u16* w2_t  = w1_t + 262144;  // [256,1024]
  u16* adj_b = w2_t + 262144;  // [96,96]

  auto tr = [&](const float* w, u16* dst, int K, int Nc) {
    int n = K * Nc;
    k_transpose<<<(n + 255) / 256, 256, 0, stream>>>(w, dst, K, Nc, n);
  };
  tr(swq, swq_t, 256, 256); tr(swk, swk_t, 256, 256);
  tr(swv, swv_t, 256, 256); tr(swp, swp_t, 256, 256);
  tr(twq, twq_t, 256, 256); tr(twk, twk_t, 256, 256);
  tr(twv, twv_t, 256, 256); tr(twp, twp_t, 256, 256);
  tr(mw1, w1_t, 256, 1024); tr(mw2, w2_t, 1024, 256);
  k_cvt<<<(EE * EE + 255) / 256, 256, 0, stream>>>(adj, adj_b, EE * EE);

  auto gemm = [&](const u16* act, const u16* Wt, const float* bias, const float* gamma,
                  u16* outB, float* Xacc, int Kd, int Nc, int lda, int ldb, int epi, int remap) {
    dim3 g(NTOK / 128, Nc / 128);
    k_gemm128<<<g, 256, 0, stream>>>(act, Wt, bias, gamma, outB, Xacc, Kd, Nc, lda, ldb, epi, remap);
  };

  int lnBlocks = NTOK / 4;

  // ---- spatial block ----
  k_ln_in<<<lnBlocks, 256, 0, stream>>>(x, X, A, n1g, n1b);                 // X=x, A=xs
  gemm(A, swq_t, nullptr, nullptr, QKV, nullptr, 256, 768, 256, 256, 0, 0); // fused QKV
  k_sp_attn<<<BB * TT * HHD, 384, 0, stream>>>(QKV, adj_b, A);              // O -> A
  gemm(A, swp_t, sbp, nullptr, Pb, nullptr, 256, 256, 256, 256, 1, 0);      // P -> Pb
  k_sp_combine<<<lnBlocks, 256, 0, stream>>>(X, A, Pb, n1g, n1b, sg, sng, snb, n2g, n2b);

  // ---- temporal block (token order [b,e,t] inside) ----
  gemm(A, twq_t, nullptr, nullptr, QKV, nullptr, 256, 768, 256, 256, 0, 1); // fused QKV, bte->bet
  k_tp_attn<<<BB * EE * HHD, 384, 0, stream>>>(QKV, A);                     // O -> A (bet)
  gemm(A, twp_t, tbp, tg, nullptr, X, 256, 256, 256, 256, 3, 2);            // X += g*(O@wp+b), bet->bte

  // ---- MLP (two 512 halves through Hh) ----
  k_ln_f32<<<lnBlocks, 256, 0, stream>>>(X, A, n3g, n3b);                   // A = xm
  gemm(A, w1_t,             mb1,       nullptr, Hh, nullptr, 256, 512, 256, 256, 2, 0);
  gemm(Hh, w2_t,            mb2,       nullptr, nullptr, X, 512, 256, 512, 1024, 3, 0);
  gemm(A, w1_t + 512 * 256, mb1 + 512, nullptr, Hh, nullptr, 256, 512, 256, 256, 2, 0);
  gemm(Hh, w2_t + 512,      nullptr,   nullptr, nullptr, X, 512, 256, 512, 1024, 3, 0);

  // ---- downsample (fp32 out) ----
  long outElems = (long)BB * TOUT * EE * CC;
  k_down<<<(int)(outElems / 4 / 256), 256, 0, stream>>>(X, out);
}

// Round 8
// 893.161 us; speedup vs baseline: 1.1246x; 1.1160x over previous
//
#include <hip/hip_runtime.h>
#include <cmath>

constexpr int BB = 8, TT = 96, EE = 96, CC = 256, HHD = 8, DDm = 32;
constexpr int NTOK = BB * TT * EE;   // 73728
constexpr int TOUT = TT / 2;         // 48

typedef unsigned short u16;
typedef short bf16x8 __attribute__((ext_vector_type(8)));
typedef float f32x4 __attribute__((ext_vector_type(4)));

__device__ __forceinline__ float bf2f(u16 u) {
  union { unsigned int i; float f; } v; v.i = ((unsigned int)u) << 16; return v.f;
}
__device__ __forceinline__ u16 f2bf(float f) {
  union { unsigned int i; float f; } v; v.f = f;
  return (u16)((v.i + 0x7FFFu + ((v.i >> 16) & 1u)) >> 16);  // RNE
}
__device__ __forceinline__ float wsum(float v) {
#pragma unroll
  for (int off = 32; off; off >>= 1) v += __shfl_xor(v, off);
  return v;
}
__device__ __forceinline__ float gelu_f(float x) {
  return 0.5f * x * (1.0f + erff(x * 0.70710678118654752f));
}
// token-order permutations: 0=id, 1=[b,t,e]->[b,e,t] position, 2=[b,e,t]->[b,t,e]
__device__ __forceinline__ int remap_row(int row, int mode) {
  if (mode == 0) return row;
  int b = row / (TT * EE);
  int rem = row - b * (TT * EE);
  if (mode == 1) { int t = rem / EE, e = rem - t * EE; return (b * EE + e) * TT + t; }
  int e = rem / TT, t = rem - e * TT;
  return (b * TT + t) * EE + e;
}

// -------- batched weight transpose+convert: 8 x [256,256] fp32 -> bf16 [Nc][K] --------
struct WPtr8 { const float* p[8]; };
__global__ void k_transpose8(WPtr8 src, u16* __restrict__ dst) {
  const float* in = src.p[blockIdx.y];
  u16* out = dst + (size_t)blockIdx.y * 65536;
  int idx = blockIdx.x * 256 + threadIdx.x;
  int k = idx >> 8, c = idx & 255;
  out[c * 256 + k] = f2bf(in[idx]);
}

// -------- weight transpose+convert: W fp32 [K][Nc] -> Wt bf16 [Nc][K] --------
__global__ void k_transpose(const float* __restrict__ in, u16* __restrict__ out, int K, int Nc, int n) {
  int idx = blockIdx.x * 256 + threadIdx.x;
  if (idx < n) {
    int k = idx / Nc, c = idx - k * Nc;
    out[c * K + k] = f2bf(in[idx]);
  }
}

// -------- fp32 -> bf16 convert (adj) --------
__global__ void k_cvt(const float* __restrict__ in, u16* __restrict__ out, int n) {
  int idx = blockIdx.x * 256 + threadIdx.x;
  if (idx < n) out[idx] = f2bf(in[idx]);
}

// ------- LN of fp32 input x -> X fp32 copy + A = LN(x)*g+b (bf16) -------
__global__ __launch_bounds__(256) void k_ln_in(const float* __restrict__ x, float* __restrict__ X,
                                               u16* __restrict__ A, const float* __restrict__ g,
                                               const float* __restrict__ b) {
  int wv = threadIdx.x >> 6, lane = threadIdx.x & 63;
  long tok = (long)blockIdx.x * 4 + wv;
  int c = lane * 4;
  long off = tok * CC + c;
  float4 v = *(const float4*)(x + off);
  float s = v.x + v.y + v.z + v.w;
  float sq = v.x * v.x + v.y * v.y + v.z * v.z + v.w * v.w;
  s = wsum(s); sq = wsum(sq);
  float m = s * (1.0f / CC);
  float rs = rsqrtf(sq * (1.0f / CC) - m * m + 1e-5f);
  *(float4*)(X + off) = v;
  float4 gv = *(const float4*)(g + c);
  float4 bv = *(const float4*)(b + c);
  ushort4 o;
  o.x = f2bf((v.x - m) * rs * gv.x + bv.x);
  o.y = f2bf((v.y - m) * rs * gv.y + bv.y);
  o.z = f2bf((v.z - m) * rs * gv.z + bv.z);
  o.w = f2bf((v.w - m) * rs * gv.w + bv.w);
  *(ushort4*)(A + off) = o;
}

// ---------------- A = LN(X fp32)*g+b ----------------
__global__ __launch_bounds__(256) void k_ln_f32(const float* __restrict__ X, u16* __restrict__ A,
                                                const float* __restrict__ g, const float* __restrict__ b) {
  int wv = threadIdx.x >> 6, lane = threadIdx.x & 63;
  long tok = (long)blockIdx.x * 4 + wv;
  int c = lane * 4;
  long off = tok * CC + c;
  float4 v = *(const float4*)(X + off);
  float s = v.x + v.y + v.z + v.w;
  float sq = v.x * v.x + v.y * v.y + v.z * v.z + v.w * v.w;
  s = wsum(s); sq = wsum(sq);
  float m = s * (1.0f / CC);
  float rs = rsqrtf(sq * (1.0f / CC) - m * m + 1e-5f);
  float4 gv = *(const float4*)(g + c);
  float4 bv = *(const float4*)(b + c);
  ushort4 o;
  o.x = f2bf((v.x - m) * rs * gv.x + bv.x);
  o.y = f2bf((v.y - m) * rs * gv.y + bv.y);
  o.z = f2bf((v.z - m) * rs * gv.z + bv.z);
  o.w = f2bf((v.w - m) * rs * gv.w + bv.w);
  *(ushort4*)(A + off) = o;
}

// ------- spatial combine: xs = LN1(X); o = LN(P)*s_ng+s_nb; X += xs + s_gamma*o; A = LN2(X) -------
__global__ __launch_bounds__(256) void k_sp_combine(float* __restrict__ X, u16* __restrict__ A,
                                                    const u16* __restrict__ P,
                                                    const float* __restrict__ n1g, const float* __restrict__ n1b,
                                                    const float* __restrict__ sg,
                                                    const float* __restrict__ s_ng, const float* __restrict__ s_nb,
                                                    const float* __restrict__ n2g, const float* __restrict__ n2b) {
  int wv = threadIdx.x >> 6, lane = threadIdx.x & 63;
  long tok = (long)blockIdx.x * 4 + wv;
  int c = lane * 4;
  long off = tok * CC + c;
  float4 xv = *(const float4*)(X + off);
  float s1 = xv.x + xv.y + xv.z + xv.w;
  float q1 = xv.x * xv.x + xv.y * xv.y + xv.z * xv.z + xv.w * xv.w;
  s1 = wsum(s1); q1 = wsum(q1);
  float m1 = s1 * (1.0f / CC);
  float r1 = rsqrtf(q1 * (1.0f / CC) - m1 * m1 + 1e-5f);
  float4 g1 = *(const float4*)(n1g + c);
  float4 b1 = *(const float4*)(n1b + c);
  float xs0 = (xv.x - m1) * r1 * g1.x + b1.x;
  float xs1 = (xv.y - m1) * r1 * g1.y + b1.y;
  float xs2 = (xv.z - m1) * r1 * g1.z + b1.z;
  float xs3 = (xv.w - m1) * r1 * g1.w + b1.w;
  ushort4 up = *(const ushort4*)(P + off);
  float4 p = make_float4(bf2f(up.x), bf2f(up.y), bf2f(up.z), bf2f(up.w));
  float s = p.x + p.y + p.z + p.w;
  float sq = p.x * p.x + p.y * p.y + p.z * p.z + p.w * p.w;
  s = wsum(s); sq = wsum(sq);
  float m = s * (1.0f / CC);
  float rs = rsqrtf(sq * (1.0f / CC) - m * m + 1e-5f);
  float4 ug = *(const float4*)(s_ng + c);
  float4 ub = *(const float4*)(s_nb + c);
  float o0 = (p.x - m) * rs * ug.x + ub.x;
  float o1 = (p.y - m) * rs * ug.y + ub.y;
  float o2 = (p.z - m) * rs * ug.z + ub.z;
  float o3 = (p.w - m) * rs * ug.w + ub.w;
  float gsg = sg[0];
  float x0 = xv.x + xs0 + gsg * o0;
  float x1 = xv.y + xs1 + gsg * o1;
  float x2 = xv.z + xs2 + gsg * o2;
  float x3 = xv.w + xs3 + gsg * o3;
  *(float4*)(X + off) = make_float4(x0, x1, x2, x3);
  float s2 = x0 + x1 + x2 + x3;
  float sq2 = x0 * x0 + x1 * x1 + x2 * x2 + x3 * x3;
  s2 = wsum(s2); sq2 = wsum(sq2);
  float m2 = s2 * (1.0f / CC);
  float rs2 = rsqrtf(sq2 * (1.0f / CC) - m2 * m2 + 1e-5f);
  float4 g2 = *(const float4*)(n2g + c);
  float4 b2 = *(const float4*)(n2b + c);
  ushort4 o;
  o.x = f2bf((x0 - m2) * rs2 * g2.x + b2.x);
  o.y = f2bf((x1 - m2) * rs2 * g2.y + b2.y);
  o.z = f2bf((x2 - m2) * rs2 * g2.z + b2.z);
  o.w = f2bf((x3 - m2) * rs2 * g2.w + b2.w);
  *(ushort4*)(A + off) = o;
}

// ---- 128x128-tile MFMA GEMM: out[M,Nc] = act[M,Kd](lda) @ Wt[Nc,Kd](ldb)^T ----
// grid = (Nc/128, M/128): consecutive blocks share the A row-tile (L2 reuse).
// epi: 0 plain; 1 +bias; 2 +bias,gelu; 3 (+bias), Xacc += gamma*val
__global__ __launch_bounds__(256) void k_gemm128(const u16* __restrict__ act, const u16* __restrict__ Wt,
                                                 const float* __restrict__ bias, const float* __restrict__ gptr,
                                                 u16* __restrict__ outB, float* __restrict__ Xacc,
                                                 int Kd, int Nc, int lda, int ldb, int epi, int remap) {
  __shared__ __align__(16) u16 As[128 * 32];   // 8 KB
  __shared__ __align__(16) u16 Bs[128 * 32];   // 8 KB
  int m0 = blockIdx.y * 128, n0 = blockIdx.x * 128;
  int tid = threadIdx.x;
  int wv = tid >> 6, lane = tid & 63, lm = lane & 15, quad = lane >> 4;
  int wr = wv >> 1, wc = wv & 1;               // wave's 64x64 quadrant
  f32x4 acc[4][4];
#pragma unroll
  for (int i = 0; i < 4; i++)
#pragma unroll
    for (int j = 0; j < 4; j++) acc[i][j] = (f32x4){0.f, 0.f, 0.f, 0.f};

  for (int kk = 0; kk < Kd; kk += 32) {
#pragma unroll
    for (int j = 0; j < 2; j++) {
      int cid = j * 256 + wv * 64 + lane;
      int row = cid >> 2, seg = cid & 3;
      const u16* ga = act + (long)(m0 + row) * lda + kk + seg * 8;
      const u16* gb = Wt + (long)(n0 + row) * ldb + kk + seg * 8;
      u16* la = &As[(j * 256 + wv * 64) * 8];
      u16* lb = &Bs[(j * 256 + wv * 64) * 8];
      __builtin_amdgcn_global_load_lds(ga, la, 16, 0, 0);
      __builtin_amdgcn_global_load_lds(gb, lb, 16, 0, 0);
    }
    __syncthreads();
    bf16x8 af[4], bfv[4];
#pragma unroll
    for (int t = 0; t < 4; t++) {
      af[t] = *(const bf16x8*)&As[(wr * 64 + t * 16 + lm) * 32 + quad * 8];
      bfv[t] = *(const bf16x8*)&Bs[(wc * 64 + t * 16 + lm) * 32 + quad * 8];
    }
#pragma unroll
    for (int ti = 0; ti < 4; ti++)
#pragma unroll
      for (int tj = 0; tj < 4; tj++)
        acc[ti][tj] = __builtin_amdgcn_mfma_f32_16x16x32_bf16(af[ti], bfv[tj], acc[ti][tj], 0, 0, 0);
    __syncthreads();
  }

  float gm = (epi == 3 && gptr) ? gptr[0] : 1.0f;
  int orows[16];
#pragma unroll
  for (int ti = 0; ti < 4; ti++)
#pragma unroll
    for (int r = 0; r < 4; r++)
      orows[ti * 4 + r] = remap_row(m0 + wr * 64 + ti * 16 + quad * 4 + r, remap);
#pragma unroll
  for (int tj = 0; tj < 4; tj++) {
    int col = n0 + wc * 64 + tj * 16 + lm;
    float bv = (epi >= 1 && bias) ? bias[col] : 0.0f;
#pragma unroll
    for (int ti = 0; ti < 4; ti++)
#pragma unroll
      for (int r = 0; r < 4; r++) {
        float vv = acc[ti][tj][r] + bv;
        if (epi == 2) vv = gelu_f(vv);
        long off = (long)orows[ti * 4 + r] * Nc + col;
        if (epi == 3) Xacc[off] += gm * vv;
        else outB[off] = f2bf(vv);
      }
  }
}

// ---- spatial attention: per (b,t,h); QKV interleaved [N,768]; S=(QK^T*adj+1)/2; O=S@V -> O[N,256] ----
__global__ __launch_bounds__(384) void k_sp_attn(const u16* __restrict__ QKV, const u16* __restrict__ adj,
                                                 u16* __restrict__ O) {
  __shared__ __align__(16) u16 Qs[96 * 32];
  __shared__ __align__(16) u16 Ks[96 * 32];
  __shared__ __align__(16) u16 Vs[96 * 32];
  __shared__ __align__(16) u16 Ss[96 * 96];
  int blk = blockIdx.x;
  int h = blk & 7, t = (blk >> 3) % TT, b = blk / (8 * TT);
  long base = ((long)(b * TT + t) * EE) * 768 + h * DDm;
  int tid = threadIdx.x;
  {
    int row = tid >> 2, seg = tid & 3;
    long goff = base + (long)row * 768 + seg * 8;
    *(uint4*)&Qs[row * 32 + seg * 8] = *(const uint4*)(QKV + goff);
    *(uint4*)&Ks[row * 32 + seg * 8] = *(const uint4*)(QKV + goff + 256);
    *(uint4*)&Vs[row * 32 + seg * 8] = *(const uint4*)(QKV + goff + 512);
#pragma unroll
    for (int i = 0; i < 3; i++) {
      int off = tid * 24 + i * 8;
      *(uint4*)&Ss[off] = *(const uint4*)(adj + off);
    }
  }
  __syncthreads();
  int wv = tid >> 6, lane = tid & 63, lm = lane & 15, quad = lane >> 4;
  bf16x8 aq = *(const bf16x8*)&Qs[(wv * 16 + lm) * 32 + quad * 8];
  f32x4 sc[6];
#pragma unroll
  for (int j = 0; j < 6; j++) {
    bf16x8 bk = *(const bf16x8*)&Ks[(j * 16 + lm) * 32 + quad * 8];
    f32x4 z = (f32x4){0.f, 0.f, 0.f, 0.f};
    sc[j] = __builtin_amdgcn_mfma_f32_16x16x32_bf16(aq, bk, z, 0, 0, 0);
  }
  u16 sv[6][4];
#pragma unroll
  for (int j = 0; j < 6; j++) {
    int col = j * 16 + lm;
#pragma unroll
    for (int r = 0; r < 4; r++) {
      int row = wv * 16 + quad * 4 + r;
      float a = bf2f(Ss[row * 96 + col]);
      sv[j][r] = f2bf((sc[j][r] * a + 1.0f) * 0.5f);
    }
  }
  __syncthreads();
#pragma unroll
  for (int j = 0; j < 6; j++) {
    int col = j * 16 + lm;
#pragma unroll
    for (int r = 0; r < 4; r++) Ss[(wv * 16 + quad * 4 + r) * 96 + col] = sv[j][r];
  }
  __syncthreads();
  f32x4 oc[2];
  oc[0] = (f32x4){0.f, 0.f, 0.f, 0.f};
  oc[1] = (f32x4){0.f, 0.f, 0.f, 0.f};
#pragma unroll
  for (int ks = 0; ks < 3; ks++) {
    bf16x8 as = *(const bf16x8*)&Ss[(wv * 16 + lm) * 96 + ks * 32 + quad * 8];
#pragma unroll
    for (int n = 0; n < 2; n++) {
      bf16x8 bv;
#pragma unroll
      for (int jj = 0; jj < 8; jj++)
        bv[jj] = (short)Vs[(ks * 32 + quad * 8 + jj) * 32 + n * 16 + lm];
      oc[n] = __builtin_amdgcn_mfma_f32_16x16x32_bf16(as, bv, oc[n], 0, 0, 0);
    }
  }
  long obase = ((long)(b * TT + t) * EE) * CC + h * DDm;
#pragma unroll
  for (int n = 0; n < 2; n++)
#pragma unroll
    for (int r = 0; r < 4; r++) {
      int row = wv * 16 + quad * 4 + r;
      O[obase + (long)row * CC + n * 16 + lm] = f2bf(oc[n][r]);
    }
}

// ---- temporal attention: per (b,e,h); QKV [b,e,t] [N,768]; REGISTER softmax; O [b,e,t] [N,256] ----
__global__ __launch_bounds__(384) void k_tp_attn(const u16* __restrict__ QKV, u16* __restrict__ O) {
  __shared__ __align__(16) u16 Qs[96 * 32];
  __shared__ __align__(16) u16 Ks[96 * 32];
  __shared__ __align__(16) u16 Vs[96 * 32];
  __shared__ __align__(16) u16 Ss[96 * 96];   // P in bf16
  int blk = blockIdx.x;
  int h = blk & 7, e = (blk >> 3) % EE, b = blk / (8 * EE);
  long base = ((long)(b * EE + e) * TT) * 768 + h * DDm;
  int tid = threadIdx.x;
  {
    int row = tid >> 2, seg = tid & 3;
    long goff = base + (long)row * 768 + seg * 8;
    *(uint4*)&Qs[row * 32 + seg * 8] = *(const uint4*)(QKV + goff);
    *(uint4*)&Ks[row * 32 + seg * 8] = *(const uint4*)(QKV + goff + 256);
    *(uint4*)&Vs[row * 32 + seg * 8] = *(const uint4*)(QKV + goff + 512);
  }
  __syncthreads();
  int wv = tid >> 6, lane = tid & 63, lm = lane & 15, quad = lane >> 4;
  bf16x8 aq = *(const bf16x8*)&Qs[(wv * 16 + lm) * 32 + quad * 8];
  f32x4 sc[6];
#pragma unroll
  for (int j = 0; j < 6; j++) {
    bf16x8 bk = *(const bf16x8*)&Ks[(j * 16 + lm) * 32 + quad * 8];
    f32x4 z = (f32x4){0.f, 0.f, 0.f, 0.f};
    sc[j] = __builtin_amdgcn_mfma_f32_16x16x32_bf16(aq, bk, z, 0, 0, 0);
  }
  const float scale = 0.17677669529663687f;  // 1/sqrt(32)
  // register softmax: row r of this lane = wv*16 + quad*4 + r; lanes sharing a row = same quad, lm=0..15
#pragma unroll
  for (int r = 0; r < 4; r++) {
    float mx = -1e30f;
#pragma unroll
    for (int j = 0; j < 6; j++) { sc[j][r] *= scale; mx = fmaxf(mx, sc[j][r]); }
#pragma unroll
    for (int mask = 1; mask < 16; mask <<= 1) mx = fmaxf(mx, __shfl_xor(mx, mask));
    float sum = 0.f;
#pragma unroll
    for (int j = 0; j < 6; j++) { float p = __expf(sc[j][r] - mx); sc[j][r] = p; sum += p; }
#pragma unroll
    for (int mask = 1; mask < 16; mask <<= 1) sum += __shfl_xor(sum, mask);
    float inv = 1.0f / sum;
#pragma unroll
    for (int j = 0; j < 6; j++) sc[j][r] *= inv;
  }
#pragma unroll
  for (int j = 0; j < 6; j++) {
    int col = j * 16 + lm;
#pragma unroll
    for (int r = 0; r < 4; r++) Ss[(wv * 16 + quad * 4 + r) * 96 + col] = f2bf(sc[j][r]);
  }
  __syncthreads();
  f32x4 oc[2];
  oc[0] = (f32x4){0.f, 0.f, 0.f, 0.f};
  oc[1] = (f32x4){0.f, 0.f, 0.f, 0.f};
#pragma unroll
  for (int ks = 0; ks < 3; ks++) {
    bf16x8 as = *(const bf16x8*)&Ss[(wv * 16 + lm) * 96 + ks * 32 + quad * 8];
#pragma unroll
    for (int n = 0; n < 2; n++) {
      bf16x8 bv;
#pragma unroll
      for (int jj = 0; jj < 8; jj++)
        bv[jj] = (short)Vs[(ks * 32 + quad * 8 + jj) * 32 + n * 16 + lm];
      oc[n] = __builtin_amdgcn_mfma_f32_16x16x32_bf16(as, bv, oc[n], 0, 0, 0);
    }
  }
  long obase = ((long)(b * EE + e) * TT) * CC + h * DDm;
#pragma unroll
  for (int n = 0; n < 2; n++)
#pragma unroll
    for (int r = 0; r < 4; r++) {
      int row = wv * 16 + quad * 4 + r;  // t index
      O[obase + (long)row * CC + n * 16 + lm] = f2bf(oc[n][r]);
    }
}

// ------- downsample: out[b,i,e,c] = 0.5*(X[b,2i,e,c] + X[b,2i+1,e,c])  (fp32 out) -------
__global__ __launch_bounds__(256) void k_down(const float* __restrict__ X, float* __restrict__ out) {
  long i4 = ((long)blockIdx.x * 256 + threadIdx.x) * 4;
  long tmp = i4;
  int c = (int)(tmp & 255); tmp >>= 8;
  int e = (int)(tmp % EE); tmp /= EE;
  int i = (int)(tmp % TOUT);
  int b = (int)(tmp / TOUT);
  long src0 = (((long)b * TT + 2 * i) * EE + e) * CC + c;
  float4 a = *(const float4*)(X + src0);
  float4 bb = *(const float4*)(X + src0 + (long)EE * CC);
  float4 o = make_float4(0.5f * (a.x + bb.x), 0.5f * (a.y + bb.y),
                         0.5f * (a.z + bb.z), 0.5f * (a.w + bb.w));
  *(float4*)(out + i4) = o;
}

extern "C" void kernel_launch(void* const* d_in, const int* in_sizes, int n_in,
                              void* d_out, int out_size, void* d_ws, size_t ws_size,
                              hipStream_t stream) {
  (void)in_sizes; (void)n_in; (void)out_size; (void)ws_size;
  const float* x   = (const float*)d_in[0];
  const float* adj = (const float*)d_in[1];
  const float* n1g = (const float*)d_in[2];
  const float* n1b = (const float*)d_in[3];
  const float* swq = (const float*)d_in[4];
  const float* swk = (const float*)d_in[5];
  const float* swv = (const float*)d_in[6];
  const float* swp = (const float*)d_in[7];
  const float* sbp = (const float*)d_in[8];
  const float* sng = (const float*)d_in[9];
  const float* snb = (const float*)d_in[10];
  const float* sg  = (const float*)d_in[11];
  const float* n2g = (const float*)d_in[12];
  const float* n2b = (const float*)d_in[13];
  const float* twq = (const float*)d_in[14];
  const float* twk = (const float*)d_in[15];
  const float* twv = (const float*)d_in[16];
  const float* twp = (const float*)d_in[17];
  const float* tbp = (const float*)d_in[18];
  const float* tg  = (const float*)d_in[19];
  const float* n3g = (const float*)d_in[20];
  const float* n3b = (const float*)d_in[21];
  const float* mw1 = (const float*)d_in[22];
  const float* mb1 = (const float*)d_in[23];
  const float* mw2 = (const float*)d_in[24];
  const float* mb2 = (const float*)d_in[25];
  float* out = (float*)d_out;

  // ---- workspace: X fp32 | A bf16 | QKV bf16 [N,768] | weights ----
  size_t nc = (size_t)NTOK * CC;
  float* X  = (float*)d_ws;
  u16* A    = (u16*)(X + nc);
  u16* QKV  = A + nc;
  u16* Pb   = QKV;
  u16* Hh   = QKV;
  u16* wts  = QKV + 3 * nc;
  u16* swq_t = wts;             // 8 contiguous C*C transposed weights
  u16* twp_t = wts + 7 * 65536;
  u16* w1_t  = wts + 8 * 65536;  // [1024,256]
  u16* w2_t  = w1_t + 262144;    // [256,1024]
  u16* adj_b = w2_t + 262144;    // [96,96]
  u16* swp_t = wts + 3 * 65536;
  u16* twq_t = wts + 4 * 65536;

  WPtr8 w8; w8.p[0] = swq; w8.p[1] = swk; w8.p[2] = swv; w8.p[3] = swp;
  w8.p[4] = twq; w8.p[5] = twk; w8.p[6] = twv; w8.p[7] = twp;
  k_transpose8<<<dim3(256, 8), 256, 0, stream>>>(w8, wts);
  k_transpose<<<(256 * 1024 + 255) / 256, 256, 0, stream>>>(mw1, w1_t, 256, 1024, 256 * 1024);
  k_transpose<<<(1024 * 256 + 255) / 256, 256, 0, stream>>>(mw2, w2_t, 1024, 256, 1024 * 256);
  k_cvt<<<(EE * EE + 255) / 256, 256, 0, stream>>>(adj, adj_b, EE * EE);

  auto gemm = [&](const u16* act, const u16* Wt, const float* bias, const float* gamma,
                  u16* outB, float* Xacc, int Kd, int Nc, int lda, int ldb, int epi, int remap) {
    dim3 g(Nc / 128, NTOK / 128);
    k_gemm128<<<g, 256, 0, stream>>>(act, Wt, bias, gamma, outB, Xacc, Kd, Nc, lda, ldb, epi, remap);
  };

  int lnBlocks = NTOK / 4;

  // ---- spatial block ----
  k_ln_in<<<lnBlocks, 256, 0, stream>>>(x, X, A, n1g, n1b);                 // X=x, A=xs
  gemm(A, swq_t, nullptr, nullptr, QKV, nullptr, 256, 768, 256, 256, 0, 0); // fused QKV
  k_sp_attn<<<BB * TT * HHD, 384, 0, stream>>>(QKV, adj_b, A);              // O -> A
  gemm(A, swp_t, sbp, nullptr, Pb, nullptr, 256, 256, 256, 256, 1, 0);      // P -> Pb
  k_sp_combine<<<lnBlocks, 256, 0, stream>>>(X, A, Pb, n1g, n1b, sg, sng, snb, n2g, n2b);

  // ---- temporal block (token order [b,e,t] inside) ----
  gemm(A, twq_t, nullptr, nullptr, QKV, nullptr, 256, 768, 256, 256, 0, 1); // fused QKV, bte->bet
  k_tp_attn<<<BB * EE * HHD, 384, 0, stream>>>(QKV, A);                     // O -> A (bet)
  gemm(A, twp_t, tbp, tg, nullptr, X, 256, 256, 256, 256, 3, 2);            // X += g*(O@wp+b), bet->bte

  // ---- MLP (two 512 halves through Hh) ----
  k_ln_f32<<<lnBlocks, 256, 0, stream>>>(X, A, n3g, n3b);                   // A = xm
  gemm(A, w1_t,             mb1,       nullptr, Hh, nullptr, 256, 512, 256, 256, 2, 0);
  gemm(Hh, w2_t,            mb2,       nullptr, nullptr, X, 512, 256, 512, 1024, 3, 0);
  gemm(A, w1_t + 512 * 256, mb1 + 512, nullptr, Hh, nullptr, 256, 512, 256, 256, 2, 0);
  gemm(Hh, w2_t + 512,      nullptr,   nullptr, nullptr, X, 512, 256, 512, 1024, 3, 0);

  // ---- downsample (fp32 out) ----
  long outElems = (long)BB * TOUT * EE * CC;
  k_down<<<(int)(outElems / 4 / 256), 256, 0, stream>>>(X, out);
}

// Round 9
// 809.287 us; speedup vs baseline: 1.2412x; 1.1036x over previous
//
#include <hip/hip_runtime.h>
#include <cmath>

constexpr int BB = 8, TT = 96, EE = 96, CC = 256, HHD = 8, DDm = 32;
constexpr int NTOK = BB * TT * EE;   // 73728
constexpr int TOUT = TT / 2;         // 48

typedef unsigned short u16;
typedef short bf16x8 __attribute__((ext_vector_type(8)));
typedef float f32x4 __attribute__((ext_vector_type(4)));

__device__ __forceinline__ float bf2f(u16 u) {
  union { unsigned int i; float f; } v; v.i = ((unsigned int)u) << 16; return v.f;
}
__device__ __forceinline__ u16 f2bf(float f) {
  union { unsigned int i; float f; } v; v.f = f;
  return (u16)((v.i + 0x7FFFu + ((v.i >> 16) & 1u)) >> 16);  // RNE
}
__device__ __forceinline__ float wsum(float v) {
#pragma unroll
  for (int off = 32; off; off >>= 1) v += __shfl_xor(v, off);
  return v;
}
__device__ __forceinline__ float gelu_f(float x) {
  return 0.5f * x * (1.0f + erff(x * 0.70710678118654752f));
}
// token-order permutations: 0=id, 1=[b,t,e]->[b,e,t] position, 2=[b,e,t]->[b,t,e]
__device__ __forceinline__ int remap_row(int row, int mode) {
  if (mode == 0) return row;
  int b = row / (TT * EE);
  int rem = row - b * (TT * EE);
  if (mode == 1) { int t = rem / EE, e = rem - t * EE; return (b * EE + e) * TT + t; }
  int e = rem / TT, t = rem - e * TT;
  return (b * TT + t) * EE + e;
}

// -------- batched weight transpose+convert: 8 x [256,256] fp32 -> bf16 [Nc][K] --------
struct WPtr8 { const float* p[8]; };
__global__ void k_transpose8(WPtr8 src, u16* __restrict__ dst) {
  const float* in = src.p[blockIdx.y];
  u16* out = dst + (size_t)blockIdx.y * 65536;
  int idx = blockIdx.x * 256 + threadIdx.x;
  int k = idx >> 8, c = idx & 255;
  out[c * 256 + k] = f2bf(in[idx]);
}

// -------- weight transpose+convert: W fp32 [K][Nc] -> Wt bf16 [Nc][K] --------
__global__ void k_transpose(const float* __restrict__ in, u16* __restrict__ out, int K, int Nc, int n) {
  int idx = blockIdx.x * 256 + threadIdx.x;
  if (idx < n) {
    int k = idx / Nc, c = idx - k * Nc;
    out[c * K + k] = f2bf(in[idx]);
  }
}

// -------- fp32 -> bf16 convert (adj) --------
__global__ void k_cvt(const float* __restrict__ in, u16* __restrict__ out, int n) {
  int idx = blockIdx.x * 256 + threadIdx.x;
  if (idx < n) out[idx] = f2bf(in[idx]);
}

// ------- LN of fp32 input x -> A = LN(x)*g+b (bf16); no X copy -------
__global__ __launch_bounds__(256) void k_ln_in(const float* __restrict__ x,
                                               u16* __restrict__ A, const float* __restrict__ g,
                                               const float* __restrict__ b) {
  int wv = threadIdx.x >> 6, lane = threadIdx.x & 63;
  long tok = (long)blockIdx.x * 4 + wv;
  int c = lane * 4;
  long off = tok * CC + c;
  float4 v = *(const float4*)(x + off);
  float s = v.x + v.y + v.z + v.w;
  float sq = v.x * v.x + v.y * v.y + v.z * v.z + v.w * v.w;
  s = wsum(s); sq = wsum(sq);
  float m = s * (1.0f / CC);
  float rs = rsqrtf(sq * (1.0f / CC) - m * m + 1e-5f);
  float4 gv = *(const float4*)(g + c);
  float4 bv = *(const float4*)(b + c);
  ushort4 o;
  o.x = f2bf((v.x - m) * rs * gv.x + bv.x);
  o.y = f2bf((v.y - m) * rs * gv.y + bv.y);
  o.z = f2bf((v.z - m) * rs * gv.z + bv.z);
  o.w = f2bf((v.w - m) * rs * gv.w + bv.w);
  *(ushort4*)(A + off) = o;
}

// ---------------- A = LN(X fp32)*g+b ----------------
__global__ __launch_bounds__(256) void k_ln_f32(const float* __restrict__ X, u16* __restrict__ A,
                                                const float* __restrict__ g, const float* __restrict__ b) {
  int wv = threadIdx.x >> 6, lane = threadIdx.x & 63;
  long tok = (long)blockIdx.x * 4 + wv;
  int c = lane * 4;
  long off = tok * CC + c;
  float4 v = *(const float4*)(X + off);
  float s = v.x + v.y + v.z + v.w;
  float sq = v.x * v.x + v.y * v.y + v.z * v.z + v.w * v.w;
  s = wsum(s); sq = wsum(sq);
  float m = s * (1.0f / CC);
  float rs = rsqrtf(sq * (1.0f / CC) - m * m + 1e-5f);
  float4 gv = *(const float4*)(g + c);
  float4 bv = *(const float4*)(b + c);
  ushort4 o;
  o.x = f2bf((v.x - m) * rs * gv.x + bv.x);
  o.y = f2bf((v.y - m) * rs * gv.y + bv.y);
  o.z = f2bf((v.z - m) * rs * gv.z + bv.z);
  o.w = f2bf((v.w - m) * rs * gv.w + bv.w);
  *(ushort4*)(A + off) = o;
}

// ------- spatial combine: reads pristine x; xs = LN1(x); o = LN(P)*s_ng+s_nb;
//         X = x + xs + s_gamma*o (first write of X); A = LN2(X) -------
__global__ __launch_bounds__(256) void k_sp_combine(const float* __restrict__ xin, float* __restrict__ X,
                                                    u16* __restrict__ A, const u16* __restrict__ P,
                                                    const float* __restrict__ n1g, const float* __restrict__ n1b,
                                                    const float* __restrict__ sg,
                                                    const float* __restrict__ s_ng, const float* __restrict__ s_nb,
                                                    const float* __restrict__ n2g, const float* __restrict__ n2b) {
  int wv = threadIdx.x >> 6, lane = threadIdx.x & 63;
  long tok = (long)blockIdx.x * 4 + wv;
  int c = lane * 4;
  long off = tok * CC + c;
  float4 xv = *(const float4*)(xin + off);
  float s1 = xv.x + xv.y + xv.z + xv.w;
  float q1 = xv.x * xv.x + xv.y * xv.y + xv.z * xv.z + xv.w * xv.w;
  s1 = wsum(s1); q1 = wsum(q1);
  float m1 = s1 * (1.0f / CC);
  float r1 = rsqrtf(q1 * (1.0f / CC) - m1 * m1 + 1e-5f);
  float4 g1 = *(const float4*)(n1g + c);
  float4 b1 = *(const float4*)(n1b + c);
  float xs0 = (xv.x - m1) * r1 * g1.x + b1.x;
  float xs1 = (xv.y - m1) * r1 * g1.y + b1.y;
  float xs2 = (xv.z - m1) * r1 * g1.z + b1.z;
  float xs3 = (xv.w - m1) * r1 * g1.w + b1.w;
  ushort4 up = *(const ushort4*)(P + off);
  float4 p = make_float4(bf2f(up.x), bf2f(up.y), bf2f(up.z), bf2f(up.w));
  float s = p.x + p.y + p.z + p.w;
  float sq = p.x * p.x + p.y * p.y + p.z * p.z + p.w * p.w;
  s = wsum(s); sq = wsum(sq);
  float m = s * (1.0f / CC);
  float rs = rsqrtf(sq * (1.0f / CC) - m * m + 1e-5f);
  float4 ug = *(const float4*)(s_ng + c);
  float4 ub = *(const float4*)(s_nb + c);
  float o0 = (p.x - m) * rs * ug.x + ub.x;
  float o1 = (p.y - m) * rs * ug.y + ub.y;
  float o2 = (p.z - m) * rs * ug.z + ub.z;
  float o3 = (p.w - m) * rs * ug.w + ub.w;
  float gsg = sg[0];
  float x0 = xv.x + xs0 + gsg * o0;
  float x1 = xv.y + xs1 + gsg * o1;
  float x2 = xv.z + xs2 + gsg * o2;
  float x3 = xv.w + xs3 + gsg * o3;
  *(float4*)(X + off) = make_float4(x0, x1, x2, x3);
  float s2 = x0 + x1 + x2 + x3;
  float sq2 = x0 * x0 + x1 * x1 + x2 * x2 + x3 * x3;
  s2 = wsum(s2); sq2 = wsum(sq2);
  float m2 = s2 * (1.0f / CC);
  float rs2 = rsqrtf(sq2 * (1.0f / CC) - m2 * m2 + 1e-5f);
  float4 g2 = *(const float4*)(n2g + c);
  float4 b2 = *(const float4*)(n2b + c);
  ushort4 o;
  o.x = f2bf((x0 - m2) * rs2 * g2.x + b2.x);
  o.y = f2bf((x1 - m2) * rs2 * g2.y + b2.y);
  o.z = f2bf((x2 - m2) * rs2 * g2.z + b2.z);
  o.w = f2bf((x3 - m2) * rs2 * g2.w + b2.w);
  *(ushort4*)(A + off) = o;
}

// ---- 128x128-tile MFMA GEMM: out[M,Nc] = act[M,Kd](lda) @ Wt[Nc,Kd](ldb)^T ----
// grid = (Nc/128, M/128). epi: 0 plain; 1 +bias; 2 +bias,gelu; 3 (+bias), Xacc += gamma*val.
// epi 0/1/2: C-tile staged through LDS -> full-line uint4 streaming writes (no RFO).
__global__ __launch_bounds__(256) void k_gemm128(const u16* __restrict__ act, const u16* __restrict__ Wt,
                                                 const float* __restrict__ bias, const float* __restrict__ gptr,
                                                 u16* __restrict__ outB, float* __restrict__ Xacc,
                                                 int Kd, int Nc, int lda, int ldb, int epi, int remap) {
  __shared__ __align__(16) u16 smem[128 * 136];  // 34 KB: As(8K)+Bs(8K) alias the C-stage
  u16* As = smem;                // 128*32
  u16* Bs = smem + 4096;         // 128*32
  int m0 = blockIdx.y * 128, n0 = blockIdx.x * 128;
  int tid = threadIdx.x;
  int wv = tid >> 6, lane = tid & 63, lm = lane & 15, quad = lane >> 4;
  int wr = wv >> 1, wc = wv & 1;
  f32x4 acc[4][4];
#pragma unroll
  for (int i = 0; i < 4; i++)
#pragma unroll
    for (int j = 0; j < 4; j++) acc[i][j] = (f32x4){0.f, 0.f, 0.f, 0.f};

  for (int kk = 0; kk < Kd; kk += 32) {
#pragma unroll
    for (int j = 0; j < 2; j++) {
      int cid = j * 256 + wv * 64 + lane;
      int row = cid >> 2, seg = cid & 3;
      const u16* ga = act + (long)(m0 + row) * lda + kk + seg * 8;
      const u16* gb = Wt + (long)(n0 + row) * ldb + kk + seg * 8;
      u16* la = &As[(j * 256 + wv * 64) * 8];
      u16* lb = &Bs[(j * 256 + wv * 64) * 8];
      __builtin_amdgcn_global_load_lds(ga, la, 16, 0, 0);
      __builtin_amdgcn_global_load_lds(gb, lb, 16, 0, 0);
    }
    __syncthreads();
    bf16x8 af[4], bfv[4];
#pragma unroll
    for (int t = 0; t < 4; t++) {
      af[t] = *(const bf16x8*)&As[(wr * 64 + t * 16 + lm) * 32 + quad * 8];
      bfv[t] = *(const bf16x8*)&Bs[(wc * 64 + t * 16 + lm) * 32 + quad * 8];
    }
#pragma unroll
    for (int ti = 0; ti < 4; ti++)
#pragma unroll
      for (int tj = 0; tj < 4; tj++)
        acc[ti][tj] = __builtin_amdgcn_mfma_f32_16x16x32_bf16(af[ti], bfv[tj], acc[ti][tj], 0, 0, 0);
    __syncthreads();
  }

  if (epi == 3) {
    float gm = gptr ? gptr[0] : 1.0f;
#pragma unroll
    for (int tj = 0; tj < 4; tj++) {
      int col = n0 + wc * 64 + tj * 16 + lm;
      float bv = bias ? bias[col] : 0.0f;
#pragma unroll
      for (int ti = 0; ti < 4; ti++)
#pragma unroll
        for (int r = 0; r < 4; r++) {
          int row = remap_row(m0 + wr * 64 + ti * 16 + quad * 4 + r, remap);
          Xacc[(long)row * Nc + col] += gm * (acc[ti][tj][r] + bv);
        }
    }
  } else {
    // stage C in LDS (row stride 136 u16 de-conflicts banks), then coalesced uint4 writes
#pragma unroll
    for (int tj = 0; tj < 4; tj++) {
      int col = wc * 64 + tj * 16 + lm;
      float bv = (epi >= 1 && bias) ? bias[n0 + col] : 0.0f;
#pragma unroll
      for (int ti = 0; ti < 4; ti++)
#pragma unroll
        for (int r = 0; r < 4; r++) {
          float vv = acc[ti][tj][r] + bv;
          if (epi == 2) vv = gelu_f(vv);
          smem[(wr * 64 + ti * 16 + quad * 4 + r) * 136 + col] = f2bf(vv);
        }
    }
    __syncthreads();
#pragma unroll
    for (int p = 0; p < 8; p++) {
      int idx = p * 256 + tid;             // 2048 uint4 chunks of the 128x128 tile
      int row = idx >> 4, c8 = idx & 15;
      int grow = remap_row(m0 + row, remap);
      *(uint4*)(outB + (long)grow * Nc + n0 + c8 * 8) = *(const uint4*)&smem[row * 136 + c8 * 8];
    }
  }
}

// ---- spatial attention: per (b,t,h); QKV interleaved [N,768]; S=(QK^T*adj+1)/2; O=S@V -> O[N,256] ----
__global__ __launch_bounds__(384) void k_sp_attn(const u16* __restrict__ QKV, const u16* __restrict__ adj,
                                                 u16* __restrict__ O) {
  __shared__ __align__(16) u16 Qs[96 * 32];
  __shared__ __align__(16) u16 Ks[96 * 32];
  __shared__ __align__(16) u16 Vs[96 * 32];
  __shared__ __align__(16) u16 Ss[96 * 96];
  int blk = blockIdx.x;
  int h = blk & 7, t = (blk >> 3) % TT, b = blk / (8 * TT);
  long base = ((long)(b * TT + t) * EE) * 768 + h * DDm;
  int tid = threadIdx.x;
  {
    int row = tid >> 2, seg = tid & 3;
    long goff = base + (long)row * 768 + seg * 8;
    *(uint4*)&Qs[row * 32 + seg * 8] = *(const uint4*)(QKV + goff);
    *(uint4*)&Ks[row * 32 + seg * 8] = *(const uint4*)(QKV + goff + 256);
    *(uint4*)&Vs[row * 32 + seg * 8] = *(const uint4*)(QKV + goff + 512);
#pragma unroll
    for (int i = 0; i < 3; i++) {
      int off = tid * 24 + i * 8;
      *(uint4*)&Ss[off] = *(const uint4*)(adj + off);
    }
  }
  __syncthreads();
  int wv = tid >> 6, lane = tid & 63, lm = lane & 15, quad = lane >> 4;
  bf16x8 aq = *(const bf16x8*)&Qs[(wv * 16 + lm) * 32 + quad * 8];
  f32x4 sc[6];
#pragma unroll
  for (int j = 0; j < 6; j++) {
    bf16x8 bk = *(const bf16x8*)&Ks[(j * 16 + lm) * 32 + quad * 8];
    f32x4 z = (f32x4){0.f, 0.f, 0.f, 0.f};
    sc[j] = __builtin_amdgcn_mfma_f32_16x16x32_bf16(aq, bk, z, 0, 0, 0);
  }
  u16 sv[6][4];
#pragma unroll
  for (int j = 0; j < 6; j++) {
    int col = j * 16 + lm;
#pragma unroll
    for (int r = 0; r < 4; r++) {
      int row = wv * 16 + quad * 4 + r;
      float a = bf2f(Ss[row * 96 + col]);
      sv[j][r] = f2bf((sc[j][r] * a + 1.0f) * 0.5f);
    }
  }
  __syncthreads();
#pragma unroll
  for (int j = 0; j < 6; j++) {
    int col = j * 16 + lm;
#pragma unroll
    for (int r = 0; r < 4; r++) Ss[(wv * 16 + quad * 4 + r) * 96 + col] = sv[j][r];
  }
  __syncthreads();
  f32x4 oc[2];
  oc[0] = (f32x4){0.f, 0.f, 0.f, 0.f};
  oc[1] = (f32x4){0.f, 0.f, 0.f, 0.f};
#pragma unroll
  for (int ks = 0; ks < 3; ks++) {
    bf16x8 as = *(const bf16x8*)&Ss[(wv * 16 + lm) * 96 + ks * 32 + quad * 8];
#pragma unroll
    for (int n = 0; n < 2; n++) {
      bf16x8 bv;
#pragma unroll
      for (int jj = 0; jj < 8; jj++)
        bv[jj] = (short)Vs[(ks * 32 + quad * 8 + jj) * 32 + n * 16 + lm];
      oc[n] = __builtin_amdgcn_mfma_f32_16x16x32_bf16(as, bv, oc[n], 0, 0, 0);
    }
  }
  long obase = ((long)(b * TT + t) * EE) * CC + h * DDm;
#pragma unroll
  for (int n = 0; n < 2; n++)
#pragma unroll
    for (int r = 0; r < 4; r++) {
      int row = wv * 16 + quad * 4 + r;
      O[obase + (long)row * CC + n * 16 + lm] = f2bf(oc[n][r]);
    }
}

// ---- temporal attention: per (b,e,h); QKV [b,e,t] [N,768]; register softmax; O [b,e,t] [N,256] ----
__global__ __launch_bounds__(384) void k_tp_attn(const u16* __restrict__ QKV, u16* __restrict__ O) {
  __shared__ __align__(16) u16 Qs[96 * 32];
  __shared__ __align__(16) u16 Ks[96 * 32];
  __shared__ __align__(16) u16 Vs[96 * 32];
  __shared__ __align__(16) u16 Ss[96 * 96];   // P in bf16
  int blk = blockIdx.x;
  int h = blk & 7, e = (blk >> 3) % EE, b = blk / (8 * EE);
  long base = ((long)(b * EE + e) * TT) * 768 + h * DDm;
  int tid = threadIdx.x;
  {
    int row = tid >> 2, seg = tid & 3;
    long goff = base + (long)row * 768 + seg * 8;
    *(uint4*)&Qs[row * 32 + seg * 8] = *(const uint4*)(QKV + goff);
    *(uint4*)&Ks[row * 32 + seg * 8] = *(const uint4*)(QKV + goff + 256);
    *(uint4*)&Vs[row * 32 + seg * 8] = *(const uint4*)(QKV + goff + 512);
  }
  __syncthreads();
  int wv = tid >> 6, lane = tid & 63, lm = lane & 15, quad = lane >> 4;
  bf16x8 aq = *(const bf16x8*)&Qs[(wv * 16 + lm) * 32 + quad * 8];
  f32x4 sc[6];
#pragma unroll
  for (int j = 0; j < 6; j++) {
    bf16x8 bk = *(const bf16x8*)&Ks[(j * 16 + lm) * 32 + quad * 8];
    f32x4 z = (f32x4){0.f, 0.f, 0.f, 0.f};
    sc[j] = __builtin_amdgcn_mfma_f32_16x16x32_bf16(aq, bk, z, 0, 0, 0);
  }
  const float scale = 0.17677669529663687f;  // 1/sqrt(32)
#pragma unroll
  for (int r = 0; r < 4; r++) {
    float mx = -1e30f;
#pragma unroll
    for (int j = 0; j < 6; j++) { sc[j][r] *= scale; mx = fmaxf(mx, sc[j][r]); }
#pragma unroll
    for (int mask = 1; mask < 16; mask <<= 1) mx = fmaxf(mx, __shfl_xor(mx, mask));
    float sum = 0.f;
#pragma unroll
    for (int j = 0; j < 6; j++) { float p = __expf(sc[j][r] - mx); sc[j][r] = p; sum += p; }
#pragma unroll
    for (int mask = 1; mask < 16; mask <<= 1) sum += __shfl_xor(sum, mask);
    float inv = 1.0f / sum;
#pragma unroll
    for (int j = 0; j < 6; j++) sc[j][r] *= inv;
  }
#pragma unroll
  for (int j = 0; j < 6; j++) {
    int col = j * 16 + lm;
#pragma unroll
    for (int r = 0; r < 4; r++) Ss[(wv * 16 + quad * 4 + r) * 96 + col] = f2bf(sc[j][r]);
  }
  __syncthreads();
  f32x4 oc[2];
  oc[0] = (f32x4){0.f, 0.f, 0.f, 0.f};
  oc[1] = (f32x4){0.f, 0.f, 0.f, 0.f};
#pragma unroll
  for (int ks = 0; ks < 3; ks++) {
    bf16x8 as = *(const bf16x8*)&Ss[(wv * 16 + lm) * 96 + ks * 32 + quad * 8];
#pragma unroll
    for (int n = 0; n < 2; n++) {
      bf16x8 bv;
#pragma unroll
      for (int jj = 0; jj < 8; jj++)
        bv[jj] = (short)Vs[(ks * 32 + quad * 8 + jj) * 32 + n * 16 + lm];
      oc[n] = __builtin_amdgcn_mfma_f32_16x16x32_bf16(as, bv, oc[n], 0, 0, 0);
    }
  }
  long obase = ((long)(b * EE + e) * TT) * CC + h * DDm;
#pragma unroll
  for (int n = 0; n < 2; n++)
#pragma unroll
    for (int r = 0; r < 4; r++) {
      int row = wv * 16 + quad * 4 + r;  // t index
      O[obase + (long)row * CC + n * 16 + lm] = f2bf(oc[n][r]);
    }
}

// ------- downsample: out[b,i,e,c] = 0.5*(X[b,2i,e,c] + X[b,2i+1,e,c])  (fp32 out) -------
__global__ __launch_bounds__(256) void k_down(const float* __restrict__ X, float* __restrict__ out) {
  long i4 = ((long)blockIdx.x * 256 + threadIdx.x) * 4;
  long tmp = i4;
  int c = (int)(tmp & 255); tmp >>= 8;
  int e = (int)(tmp % EE); tmp /= EE;
  int i = (int)(tmp % TOUT);
  int b = (int)(tmp / TOUT);
  long src0 = (((long)b * TT + 2 * i) * EE + e) * CC + c;
  float4 a = *(const float4*)(X + src0);
  float4 bb = *(const float4*)(X + src0 + (long)EE * CC);
  float4 o = make_float4(0.5f * (a.x + bb.x), 0.5f * (a.y + bb.y),
                         0.5f * (a.z + bb.z), 0.5f * (a.w + bb.w));
  *(float4*)(out + i4) = o;
}

extern "C" void kernel_launch(void* const* d_in, const int* in_sizes, int n_in,
                              void* d_out, int out_size, void* d_ws, size_t ws_size,
                              hipStream_t stream) {
  (void)in_sizes; (void)n_in; (void)out_size; (void)ws_size;
  const float* x   = (const float*)d_in[0];
  const float* adj = (const float*)d_in[1];
  const float* n1g = (const float*)d_in[2];
  const float* n1b = (const float*)d_in[3];
  const float* swq = (const float*)d_in[4];
  const float* swk = (const float*)d_in[5];
  const float* swv = (const float*)d_in[6];
  const float* swp = (const float*)d_in[7];
  const float* sbp = (const float*)d_in[8];
  const float* sng = (const float*)d_in[9];
  const float* snb = (const float*)d_in[10];
  const float* sg  = (const float*)d_in[11];
  const float* n2g = (const float*)d_in[12];
  const float* n2b = (const float*)d_in[13];
  const float* twq = (const float*)d_in[14];
  const float* twk = (const float*)d_in[15];
  const float* twv = (const float*)d_in[16];
  const float* twp = (const float*)d_in[17];
  const float* tbp = (const float*)d_in[18];
  const float* tg  = (const float*)d_in[19];
  const float* n3g = (const float*)d_in[20];
  const float* n3b = (const float*)d_in[21];
  const float* mw1 = (const float*)d_in[22];
  const float* mb1 = (const float*)d_in[23];
  const float* mw2 = (const float*)d_in[24];
  const float* mb2 = (const float*)d_in[25];
  float* out = (float*)d_out;

  // ---- workspace: X fp32 | A bf16 | QKV bf16 [N,768] | weights ----
  size_t nc = (size_t)NTOK * CC;
  float* X  = (float*)d_ws;
  u16* A    = (u16*)(X + nc);
  u16* QKV  = A + nc;
  u16* Pb   = QKV;
  u16* Hh   = QKV;    // MLP: [N/2, 1024] = 75.5 MB fits in QKV (113 MB)
  u16* wts  = QKV + 3 * nc;
  u16* swq_t = wts;
  u16* swp_t = wts + 3 * 65536;
  u16* twq_t = wts + 4 * 65536;
  u16* twp_t = wts + 7 * 65536;
  u16* w1_t  = wts + 8 * 65536;  // [1024,256]
  u16* w2_t  = w1_t + 262144;    // [256,1024]
  u16* adj_b = w2_t + 262144;    // [96,96]

  WPtr8 w8; w8.p[0] = swq; w8.p[1] = swk; w8.p[2] = swv; w8.p[3] = swp;
  w8.p[4] = twq; w8.p[5] = twk; w8.p[6] = twv; w8.p[7] = twp;
  k_transpose8<<<dim3(256, 8), 256, 0, stream>>>(w8, wts);
  k_transpose<<<(256 * 1024 + 255) / 256, 256, 0, stream>>>(mw1, w1_t, 256, 1024, 256 * 1024);
  k_transpose<<<(1024 * 256 + 255) / 256, 256, 0, stream>>>(mw2, w2_t, 1024, 256, 1024 * 256);
  k_cvt<<<(EE * EE + 255) / 256, 256, 0, stream>>>(adj, adj_b, EE * EE);

  auto gemm = [&](const u16* act, const u16* Wt, const float* bias, const float* gamma,
                  u16* outB, float* Xacc, int Kd, int Nc, int lda, int ldb, int epi, int remap, int M) {
    dim3 g(Nc / 128, M / 128);
    k_gemm128<<<g, 256, 0, stream>>>(act, Wt, bias, gamma, outB, Xacc, Kd, Nc, lda, ldb, epi, remap);
  };

  int lnBlocks = NTOK / 4;

  // ---- spatial block ----
  k_ln_in<<<lnBlocks, 256, 0, stream>>>(x, A, n1g, n1b);                          // A = xs
  gemm(A, swq_t, nullptr, nullptr, QKV, nullptr, 256, 768, 256, 256, 0, 0, NTOK); // fused QKV
  k_sp_attn<<<BB * TT * HHD, 384, 0, stream>>>(QKV, adj_b, A);                    // O -> A
  gemm(A, swp_t, sbp, nullptr, Pb, nullptr, 256, 256, 256, 256, 1, 0, NTOK);      // P -> Pb
  k_sp_combine<<<lnBlocks, 256, 0, stream>>>(x, X, A, Pb, n1g, n1b, sg, sng, snb, n2g, n2b);

  // ---- temporal block (token order [b,e,t] inside) ----
  gemm(A, twq_t, nullptr, nullptr, QKV, nullptr, 256, 768, 256, 256, 0, 1, NTOK); // fused QKV, bte->bet
  k_tp_attn<<<BB * EE * HHD, 384, 0, stream>>>(QKV, A);                           // O -> A (bet)
  gemm(A, twp_t, tbp, tg, nullptr, X, 256, 256, 256, 256, 3, 2, NTOK);            // X += g*(O@wp+b), bet->bte

  // ---- MLP: token-split halves, full HID=1024 each (X RMW once per token) ----
  k_ln_f32<<<lnBlocks, 256, 0, stream>>>(X, A, n3g, n3b);                         // A = xm
  for (int hf = 0; hf < 2; hf++) {
    long r0 = (long)hf * (NTOK / 2);
    gemm(A + r0 * CC, w1_t, mb1, nullptr, Hh, nullptr, 256, 1024, 256, 256, 2, 0, NTOK / 2);
    gemm(Hh, w2_t, mb2, nullptr, nullptr, X + r0 * CC, 1024, 256, 1024, 1024, 3, 0, NTOK / 2);
  }

  // ---- downsample (fp32 out) ----
  long outElems = (long)BB * TOUT * EE * CC;
  k_down<<<(int)(outElems / 4 / 256), 256, 0, stream>>>(X, out);
}